// Round 1
// baseline (3611.355 us; speedup 1.0000x reference)
//
#include <hip/hip_runtime.h>

#define N_NODES 100000
#define N_EDGES 3200000
#define N_LBL   200000
#define C1 128
#define C2 64

// ---------------------------------------------------------------------------
// 1) degree: deg[d] = (#edges with dst==d) + 1 (self loop added later)
__global__ void deg_kernel(const int* __restrict__ ei, int* __restrict__ degi) {
    int i = blockIdx.x * blockDim.x + threadIdx.x;
    if (i < N_EDGES) atomicAdd(&degi[ei[N_EDGES + i]], 1);
}

// 2) inv_sqrt[n] = rsqrt(deg[n]+1)   (deg>=1 always, self loop)
__global__ void inv_kernel(const int* __restrict__ degi, float* __restrict__ inv) {
    int i = blockIdx.x * blockDim.x + threadIdx.x;
    if (i < N_NODES) inv[i] = rsqrtf((float)(degi[i] + 1));
}

// 3) xs[n] = inv[n]*x[n]  (4 floats); aggX init = xs[n]  (self-loop term)
__global__ void scale_x_kernel(const float4* __restrict__ x, const float* __restrict__ inv,
                               float4* __restrict__ xs, float4* __restrict__ aggX) {
    int n = blockIdx.x * blockDim.x + threadIdx.x;
    if (n < N_NODES) {
        float s = inv[n];
        float4 v = x[n];
        v.x *= s; v.y *= s; v.z *= s; v.w *= s;
        xs[n] = v; aggX[n] = v;
    }
}

// 4) scatter 4-dim messages: aggX[dst] += xs[src]   (1 thread / edge)
__global__ void scatter_x_kernel(const int* __restrict__ ei, const float4* __restrict__ xs,
                                 float* __restrict__ aggX) {
    int e = blockIdx.x * blockDim.x + threadIdx.x;
    if (e >= N_EDGES) return;
    int s = ei[e], d = ei[N_EDGES + e];
    float4 v = xs[s];
    float* a = aggX + (size_t)d * 4;
    atomicAdd(a + 0, v.x); atomicAdd(a + 1, v.y);
    atomicAdd(a + 2, v.z); atomicAdd(a + 3, v.w);
}

// 5) h1[n][c] = relu( (inv[n]*aggX[n]) @ W1[:,c] + b1[c] )
//    thread = (node, 4 channels); W1/b1 staged in LDS
__global__ __launch_bounds__(256) void gemm1_kernel(const float4* __restrict__ aggX,
        const float* __restrict__ inv, const float* __restrict__ W1,
        const float* __restrict__ b1, float4* __restrict__ h1) {
    __shared__ float w[4 * C1];
    __shared__ float bs[C1];
    int tid = threadIdx.x;
    w[tid] = W1[tid]; w[tid + 256] = W1[tid + 256];
    if (tid < C1) bs[tid] = b1[tid];
    __syncthreads();
    int gid = blockIdx.x * 256 + tid;
    int q = gid & 31;           // channel-quad 0..31
    int n = gid >> 5;
    if (n >= N_NODES) return;
    float s = inv[n];
    float4 t = aggX[n];
    t.x *= s; t.y *= s; t.z *= s; t.w *= s;
    int c = q * 4;
    float4 o;
    o.x = fmaxf(t.x*w[c+0] + t.y*w[C1+c+0] + t.z*w[2*C1+c+0] + t.w*w[3*C1+c+0] + bs[c+0], 0.f);
    o.y = fmaxf(t.x*w[c+1] + t.y*w[C1+c+1] + t.z*w[2*C1+c+1] + t.w*w[3*C1+c+1] + bs[c+1], 0.f);
    o.z = fmaxf(t.x*w[c+2] + t.y*w[C1+c+2] + t.z*w[2*C1+c+2] + t.w*w[3*C1+c+2] + bs[c+2], 0.f);
    o.w = fmaxf(t.x*w[c+3] + t.y*w[C1+c+3] + t.z*w[2*C1+c+3] + t.w*w[3*C1+c+3] + bs[c+3], 0.f);
    h1[(size_t)n * 32 + q] = o;
}

// 6) hs2[n] = inv[n]*(h1[n] @ W2); acc2 init = hs2.
//    Block: 64 nodes. LDS: W2 (32KB) + 64 h1 rows (32KB). Thread: 4 nodes x 4 cols.
__global__ __launch_bounds__(256) void gemm2_kernel(const float* __restrict__ h1,
        const float* __restrict__ W2, const float* __restrict__ inv,
        float4* __restrict__ hs2, float4* __restrict__ acc2) {
    __shared__ float w[C1 * C2];     // 32 KB
    __shared__ float rows[64 * C1];  // 32 KB
    int tid = threadIdx.x;
    int base = blockIdx.x * 64;
    for (int i = tid; i < C1 * C2; i += 256) w[i] = W2[i];
    {
        const float4* h4 = (const float4*)(h1 + (size_t)base * C1);
        float4* r4 = (float4*)rows;
        int lim = (N_NODES - base < 64 ? N_NODES - base : 64) * (C1 / 4);
        for (int i = tid; i < 64 * (C1 / 4); i += 256)
            if (i < lim) r4[i] = h4[i];
    }
    __syncthreads();
    int q = tid & 15;        // col-quad 0..15
    int ng = tid >> 4;       // node group 0..15 (4 nodes each)
    float4 acc[4];
    #pragma unroll
    for (int j = 0; j < 4; ++j) acc[j] = make_float4(0.f, 0.f, 0.f, 0.f);
    #pragma unroll 4
    for (int k = 0; k < C1; ++k) {
        float4 wv = *(const float4*)(w + k * C2 + q * 4);
        #pragma unroll
        for (int j = 0; j < 4; ++j) {
            float r = rows[(ng * 4 + j) * C1 + k];
            acc[j].x += r * wv.x; acc[j].y += r * wv.y;
            acc[j].z += r * wv.z; acc[j].w += r * wv.w;
        }
    }
    #pragma unroll
    for (int j = 0; j < 4; ++j) {
        int n = base + ng * 4 + j;
        if (n < N_NODES) {
            float s = inv[n];
            float4 o = acc[j];
            o.x *= s; o.y *= s; o.z *= s; o.w *= s;
            hs2[(size_t)n * (C2 / 4) + q]  = o;
            acc2[(size_t)n * (C2 / 4) + q] = o;
        }
    }
}

// 7) scatter 64-dim messages: acc2[dst] += hs2[src]   (16 threads / edge, float4 each)
__global__ void scatter2_kernel(const int* __restrict__ ei, const float4* __restrict__ hs2,
                                float* __restrict__ acc2) {
    int gid = blockIdx.x * blockDim.x + threadIdx.x;
    int e = gid >> 4;
    if (e >= N_EDGES) return;
    int q = gid & 15;
    int s = ei[e], d = ei[N_EDGES + e];
    float4 v = hs2[(size_t)s * 16 + q];
    float* a = acc2 + (size_t)d * C2 + (size_t)q * 4;
    atomicAdd(a + 0, v.x); atomicAdd(a + 1, v.y);
    atomicAdd(a + 2, v.z); atomicAdd(a + 3, v.w);
}

// 8) decode: z = inv[n]*acc2[n] + b2 applied on the fly;
//    logits[e] = dot(z[a], z[b]) over 64 dims. 16 lanes/edge + xor-shuffle reduce.
__global__ void decode_kernel(const int* __restrict__ eli, const float4* __restrict__ acc2,
                              const float* __restrict__ inv, const float4* __restrict__ b2,
                              float* __restrict__ out) {
    int gid = blockIdx.x * blockDim.x + threadIdx.x;
    int e = gid >> 4;
    if (e >= N_LBL) return;
    int q = gid & 15;
    int a = eli[e], b = eli[N_LBL + e];
    float sa = inv[a], sb = inv[b];
    float4 bb = b2[q];
    float4 va = acc2[(size_t)a * 16 + q];
    float4 vb = acc2[(size_t)b * 16 + q];
    va.x = va.x * sa + bb.x; va.y = va.y * sa + bb.y;
    va.z = va.z * sa + bb.z; va.w = va.w * sa + bb.w;
    vb.x = vb.x * sb + bb.x; vb.y = vb.y * sb + bb.y;
    vb.z = vb.z * sb + bb.z; vb.w = vb.w * sb + bb.w;
    float p = va.x * vb.x + va.y * vb.y + va.z * vb.z + va.w * vb.w;
    p += __shfl_xor(p, 8);
    p += __shfl_xor(p, 4);
    p += __shfl_xor(p, 2);
    p += __shfl_xor(p, 1);
    if (q == 0) out[e] = p;
}

extern "C" void kernel_launch(void* const* d_in, const int* in_sizes, int n_in,
                              void* d_out, int out_size, void* d_ws, size_t ws_size,
                              hipStream_t stream) {
    const float* x  = (const float*)d_in[0];
    const int*   ei = (const int*)d_in[1];
    const int*  eli = (const int*)d_in[2];
    const float* W1 = (const float*)d_in[3];
    const float* b1 = (const float*)d_in[4];
    const float* W2 = (const float*)d_in[5];
    const float* b2 = (const float*)d_in[6];
    float* out = (float*)d_out;

    // workspace layout (all 16B aligned): ~106.4 MB total
    char* p = (char*)d_ws;
    int*   degi = (int*)p;    p += (size_t)N_NODES * 4;
    float* inv  = (float*)p;  p += (size_t)N_NODES * 4;
    float* xs   = (float*)p;  p += (size_t)N_NODES * 16;
    float* aggX = (float*)p;  p += (size_t)N_NODES * 16;
    float* h1   = (float*)p;  p += (size_t)N_NODES * C1 * 4;
    float* hs2  = (float*)p;  p += (size_t)N_NODES * C2 * 4;
    float* acc2 = (float*)p;  p += (size_t)N_NODES * C2 * 4;

    hipMemsetAsync(degi, 0, (size_t)N_NODES * 4, stream);
    deg_kernel<<<(N_EDGES + 255) / 256, 256, 0, stream>>>(ei, degi);
    inv_kernel<<<(N_NODES + 255) / 256, 256, 0, stream>>>(degi, inv);
    scale_x_kernel<<<(N_NODES + 255) / 256, 256, 0, stream>>>((const float4*)x, inv,
                                                              (float4*)xs, (float4*)aggX);
    scatter_x_kernel<<<(N_EDGES + 255) / 256, 256, 0, stream>>>(ei, (const float4*)xs, aggX);
    gemm1_kernel<<<(N_NODES * 32 + 255) / 256, 256, 0, stream>>>((const float4*)aggX, inv,
                                                                 W1, b1, (float4*)h1);
    gemm2_kernel<<<(N_NODES + 63) / 64, 256, 0, stream>>>(h1, W2, inv,
                                                          (float4*)hs2, (float4*)acc2);
    scatter2_kernel<<<((size_t)N_EDGES * 16 + 255) / 256, 256, 0, stream>>>(
        ei, (const float4*)hs2, acc2);
    decode_kernel<<<((size_t)N_LBL * 16 + 255) / 256, 256, 0, stream>>>(
        eli, (const float4*)acc2, inv, (const float4*)b2, out);
}

// Round 2
// 780.010 us; speedup vs baseline: 4.6299x; 4.6299x over previous
//
#include <hip/hip_runtime.h>

#define N_NODES 100000
#define N_EDGES 3200000
#define N_LBL   200000
#define C1 128
#define C2 64

__device__ __forceinline__ float4 f4add(float4 a, float4 b) {
    return make_float4(a.x + b.x, a.y + b.y, a.z + b.z, a.w + b.w);
}

// ---------------------------------------------------------------------------
// 1) degree: degi[d] = #edges with dst==d
__global__ void deg_kernel(const int* __restrict__ ei, int* __restrict__ degi) {
    int i = blockIdx.x * blockDim.x + threadIdx.x;
    if (i < N_EDGES) atomicAdd(&degi[ei[N_EDGES + i]], 1);
}

// 2) inv_sqrt[n] = rsqrt(deg[n]+1)
__global__ void inv_kernel(const int* __restrict__ degi, float* __restrict__ inv) {
    int i = blockIdx.x * blockDim.x + threadIdx.x;
    if (i < N_NODES) inv[i] = rsqrtf((float)(degi[i] + 1));
}

// 3) exclusive prefix scan of degi -> offs[0..N_NODES]  (single 1024-thread block)
__global__ __launch_bounds__(1024) void scan_kernel(const int* __restrict__ degi,
                                                    int* __restrict__ offs) {
    __shared__ int wsum[16];
    int tid = threadIdx.x;
    int lane = tid & 63, w = tid >> 6;
    int carry = 0;
    for (int base = 0; base < N_NODES; base += 1024) {
        int i = base + tid;
        int v = (i < N_NODES) ? degi[i] : 0;
        int incl = v;
        #pragma unroll
        for (int off = 1; off < 64; off <<= 1) {
            int t = __shfl_up(incl, off);
            if (lane >= off) incl += t;
        }
        if (lane == 63) wsum[w] = incl;
        __syncthreads();
        if (w == 0 && lane < 16) {
            int s = wsum[lane];
            #pragma unroll
            for (int off = 1; off < 16; off <<= 1) {
                int t = __shfl_up(s, off);
                if (lane >= off) s += t;
            }
            wsum[lane] = s;
        }
        __syncthreads();
        int wbase = (w == 0) ? 0 : wsum[w - 1];
        if (i < N_NODES) offs[i] = carry + wbase + incl - v;
        carry += wsum[15];
        __syncthreads();
    }
    if (tid == 0) offs[N_NODES] = N_EDGES;
}

// 4) counting-sort placement: srcs[offs[d] + cursor[d]++] = s
__global__ void place_kernel(const int* __restrict__ ei, const int* __restrict__ offs,
                             int* __restrict__ cursor, int* __restrict__ srcs) {
    int e = blockIdx.x * blockDim.x + threadIdx.x;
    if (e >= N_EDGES) return;
    int s = ei[e], d = ei[N_EDGES + e];
    int pos = offs[d] + atomicAdd(&cursor[d], 1);
    srcs[pos] = s;
}

// 5) xs[n] = inv[n]*x[n]
__global__ void scale_x_kernel(const float4* __restrict__ x, const float* __restrict__ inv,
                               float4* __restrict__ xs) {
    int n = blockIdx.x * blockDim.x + threadIdx.x;
    if (n < N_NODES) {
        float s = inv[n];
        float4 v = x[n];
        v.x *= s; v.y *= s; v.z *= s; v.w *= s;
        xs[n] = v;
    }
}

// 6) gather-aggregate layer 1: aggX[n] = xs[n] + sum_{src in N(n)} xs[src]
//    (1 thread / node)
__global__ void agg1_kernel(const float4* __restrict__ xs, const int* __restrict__ offs,
                            const int* __restrict__ srcs, float4* __restrict__ aggX) {
    int n = blockIdx.x * blockDim.x + threadIdx.x;
    if (n >= N_NODES) return;
    float4 acc = xs[n];
    int b = offs[n], e = offs[n + 1];
    for (int j = b; j < e; ++j) acc = f4add(acc, xs[srcs[j]]);
    aggX[n] = acc;
}

// 7) h1[n][c] = relu( (inv[n]*aggX[n]) @ W1[:,c] + b1[c] )
__global__ __launch_bounds__(256) void gemm1_kernel(const float4* __restrict__ aggX,
        const float* __restrict__ inv, const float* __restrict__ W1,
        const float* __restrict__ b1, float4* __restrict__ h1) {
    __shared__ float w[4 * C1];
    __shared__ float bs[C1];
    int tid = threadIdx.x;
    w[tid] = W1[tid]; w[tid + 256] = W1[tid + 256];
    if (tid < C1) bs[tid] = b1[tid];
    __syncthreads();
    int gid = blockIdx.x * 256 + tid;
    int q = gid & 31;
    int n = gid >> 5;
    if (n >= N_NODES) return;
    float s = inv[n];
    float4 t = aggX[n];
    t.x *= s; t.y *= s; t.z *= s; t.w *= s;
    int c = q * 4;
    float4 o;
    o.x = fmaxf(t.x*w[c+0] + t.y*w[C1+c+0] + t.z*w[2*C1+c+0] + t.w*w[3*C1+c+0] + bs[c+0], 0.f);
    o.y = fmaxf(t.x*w[c+1] + t.y*w[C1+c+1] + t.z*w[2*C1+c+1] + t.w*w[3*C1+c+1] + bs[c+1], 0.f);
    o.z = fmaxf(t.x*w[c+2] + t.y*w[C1+c+2] + t.z*w[2*C1+c+2] + t.w*w[3*C1+c+2] + bs[c+2], 0.f);
    o.w = fmaxf(t.x*w[c+3] + t.y*w[C1+c+3] + t.z*w[2*C1+c+3] + t.w*w[3*C1+c+3] + bs[c+3], 0.f);
    h1[(size_t)n * 32 + q] = o;
}

// 8) hs2[n] = inv[n]*(h1[n] @ W2)
__global__ __launch_bounds__(256) void gemm2_kernel(const float* __restrict__ h1,
        const float* __restrict__ W2, const float* __restrict__ inv,
        float4* __restrict__ hs2) {
    __shared__ float w[C1 * C2];     // 32 KB
    __shared__ float rows[64 * C1];  // 32 KB
    int tid = threadIdx.x;
    int base = blockIdx.x * 64;
    for (int i = tid; i < C1 * C2; i += 256) w[i] = W2[i];
    {
        const float4* h4 = (const float4*)(h1 + (size_t)base * C1);
        float4* r4 = (float4*)rows;
        int lim = (N_NODES - base < 64 ? N_NODES - base : 64) * (C1 / 4);
        for (int i = tid; i < 64 * (C1 / 4); i += 256)
            if (i < lim) r4[i] = h4[i];
    }
    __syncthreads();
    int q = tid & 15;
    int ng = tid >> 4;
    float4 acc[4];
    #pragma unroll
    for (int j = 0; j < 4; ++j) acc[j] = make_float4(0.f, 0.f, 0.f, 0.f);
    #pragma unroll 4
    for (int k = 0; k < C1; ++k) {
        float4 wv = *(const float4*)(w + k * C2 + q * 4);
        #pragma unroll
        for (int j = 0; j < 4; ++j) {
            float r = rows[(ng * 4 + j) * C1 + k];
            acc[j].x += r * wv.x; acc[j].y += r * wv.y;
            acc[j].z += r * wv.z; acc[j].w += r * wv.w;
        }
    }
    #pragma unroll
    for (int j = 0; j < 4; ++j) {
        int n = base + ng * 4 + j;
        if (n < N_NODES) {
            float s = inv[n];
            float4 o = acc[j];
            o.x *= s; o.y *= s; o.z *= s; o.w *= s;
            hs2[(size_t)n * (C2 / 4) + q] = o;
        }
    }
}

// 9) gather-aggregate layer 2 + epilogue:
//    z[n] = inv[n] * ( hs2[n] + sum_{src} hs2[src] ) + b2     (16 lanes / node)
__global__ void agg2_kernel(const float4* __restrict__ hs2, const int* __restrict__ offs,
                            const int* __restrict__ srcs, const float* __restrict__ inv,
                            const float4* __restrict__ b2, float4* __restrict__ z) {
    int gid = blockIdx.x * blockDim.x + threadIdx.x;
    int n = gid >> 4;
    if (n >= N_NODES) return;
    int q = gid & 15;
    float4 acc = hs2[(size_t)n * 16 + q];
    int b = offs[n], e = offs[n + 1];
    for (int j = b; j < e; ++j) {
        int s = srcs[j];
        acc = f4add(acc, hs2[(size_t)s * 16 + q]);
    }
    float s = inv[n];
    float4 bb = b2[q];
    acc.x = acc.x * s + bb.x; acc.y = acc.y * s + bb.y;
    acc.z = acc.z * s + bb.z; acc.w = acc.w * s + bb.w;
    z[(size_t)n * 16 + q] = acc;
}

// 10) decode: logits[e] = dot(z[a], z[b])   (16 lanes / edge, xor-shuffle reduce)
__global__ void decode_kernel(const int* __restrict__ eli, const float4* __restrict__ z,
                              float* __restrict__ out) {
    int gid = blockIdx.x * blockDim.x + threadIdx.x;
    int e = gid >> 4;
    if (e >= N_LBL) return;
    int q = gid & 15;
    int a = eli[e], b = eli[N_LBL + e];
    float4 va = z[(size_t)a * 16 + q];
    float4 vb = z[(size_t)b * 16 + q];
    float p = va.x * vb.x + va.y * vb.y + va.z * vb.z + va.w * vb.w;
    p += __shfl_xor(p, 8);
    p += __shfl_xor(p, 4);
    p += __shfl_xor(p, 2);
    p += __shfl_xor(p, 1);
    if (q == 0) out[e] = p;
}

extern "C" void kernel_launch(void* const* d_in, const int* in_sizes, int n_in,
                              void* d_out, int out_size, void* d_ws, size_t ws_size,
                              hipStream_t stream) {
    const float* x  = (const float*)d_in[0];
    const int*   ei = (const int*)d_in[1];
    const int*  eli = (const int*)d_in[2];
    const float* W1 = (const float*)d_in[3];
    const float* b1 = (const float*)d_in[4];
    const float* W2 = (const float*)d_in[5];
    const float* b2 = (const float*)d_in[6];
    float* out = (float*)d_out;

    // workspace layout (16B aligned). Total ~95 MB (z aliases h1's buffer).
    char* p = (char*)d_ws;
    int*   degi   = (int*)p;    p += (size_t)N_NODES * 4;
    float* inv    = (float*)p;  p += (size_t)N_NODES * 4;
    int*   offs   = (int*)p;    p += (size_t)(N_NODES + 4) * 4;
    int*   cursor = (int*)p;    p += (size_t)N_NODES * 4;
    int*   srcs   = (int*)p;    p += (size_t)N_EDGES * 4;
    float* xs     = (float*)p;  p += (size_t)N_NODES * 16;
    float* aggX   = (float*)p;  p += (size_t)N_NODES * 16;
    float* h1     = (float*)p;  p += (size_t)N_NODES * C1 * 4;
    float* hs2    = (float*)p;  p += (size_t)N_NODES * C2 * 4;
    float* z      = h1;  // h1 dead after gemm2; reuse (25.6 MB <= 51.2 MB)

    hipMemsetAsync(degi, 0, (size_t)N_NODES * 4, stream);
    hipMemsetAsync(cursor, 0, (size_t)N_NODES * 4, stream);
    deg_kernel<<<(N_EDGES + 255) / 256, 256, 0, stream>>>(ei, degi);
    inv_kernel<<<(N_NODES + 255) / 256, 256, 0, stream>>>(degi, inv);
    scan_kernel<<<1, 1024, 0, stream>>>(degi, offs);
    place_kernel<<<(N_EDGES + 255) / 256, 256, 0, stream>>>(ei, offs, cursor, srcs);
    scale_x_kernel<<<(N_NODES + 255) / 256, 256, 0, stream>>>((const float4*)x, inv,
                                                              (float4*)xs);
    agg1_kernel<<<(N_NODES + 255) / 256, 256, 0, stream>>>((const float4*)xs, offs, srcs,
                                                           (float4*)aggX);
    gemm1_kernel<<<(N_NODES * 32 + 255) / 256, 256, 0, stream>>>((const float4*)aggX, inv,
                                                                 W1, b1, (float4*)h1);
    gemm2_kernel<<<(N_NODES + 63) / 64, 256, 0, stream>>>(h1, W2, inv, (float4*)hs2);
    agg2_kernel<<<((size_t)N_NODES * 16 + 255) / 256, 256, 0, stream>>>(
        (const float4*)hs2, offs, srcs, inv, (const float4*)b2, (float4*)z);
    decode_kernel<<<((size_t)N_LBL * 16 + 255) / 256, 256, 0, stream>>>(
        eli, (const float4*)z, out);
}

// Round 3
// 433.525 us; speedup vs baseline: 8.3302x; 1.7992x over previous
//
#include <hip/hip_runtime.h>

#define N_NODES 100000
#define N_EDGES 3200000
#define N_LBL   200000
#define C1 128
#define C2 64

// bucketing: nodes grouped by (node >> BSH), 128 nodes per bucket
#define BSH   7
#define NPB   128
#define NBKT  ((N_NODES + NPB - 1) / NPB)   // 782
#define NCB   250                            // counting/placing blocks
#define CHUNK (N_EDGES / NCB)                // 12800 edges per block (exact)

__device__ __forceinline__ float4 f4add(float4 a, float4 b) {
    return make_float4(a.x + b.x, a.y + b.y, a.z + b.z, a.w + b.w);
}

// ---------------------------------------------------------------------------
// k1) per-block LDS histogram of dst-buckets -> global bucket totals
__global__ __launch_bounds__(256) void count_kernel(const int* __restrict__ ei,
                                                    int* __restrict__ bucket_total) {
    __shared__ int hist[NBKT];
    int tid = threadIdx.x;
    for (int i = tid; i < NBKT; i += 256) hist[i] = 0;
    __syncthreads();
    int base = blockIdx.x * CHUNK;
    for (int it = 0; it < CHUNK / 256; ++it) {
        int d = ei[N_EDGES + base + it * 256 + tid];
        atomicAdd(&hist[d >> BSH], 1);
    }
    __syncthreads();
    for (int i = tid; i < NBKT; i += 256)
        if (hist[i]) atomicAdd(&bucket_total[i], hist[i]);
}

// k2) exclusive scan of 782 bucket totals -> boffs[0..782], init bcursor
__global__ __launch_bounds__(1024) void bscan_kernel(const int* __restrict__ bucket_total,
        int* __restrict__ boffs, int* __restrict__ bcursor, int* __restrict__ offs) {
    __shared__ int wsum[16];
    int tid = threadIdx.x;
    int lane = tid & 63, w = tid >> 6;
    int v = (tid < NBKT) ? bucket_total[tid] : 0;
    int incl = v;
    #pragma unroll
    for (int off = 1; off < 64; off <<= 1) {
        int t = __shfl_up(incl, off);
        if (lane >= off) incl += t;
    }
    if (lane == 63) wsum[w] = incl;
    __syncthreads();
    if (w == 0 && lane < 16) {
        int s = wsum[lane];
        #pragma unroll
        for (int off = 1; off < 16; off <<= 1) {
            int t = __shfl_up(s, off);
            if (lane >= off) s += t;
        }
        wsum[lane] = s;
    }
    __syncthreads();
    int excl = incl - v + ((w == 0) ? 0 : wsum[w - 1]);
    if (tid <= NBKT) boffs[tid] = excl;
    if (tid < NBKT)  bcursor[tid] = excl;
    if (tid == 0) offs[N_NODES] = N_EDGES;
}

// k3) bucketize edges into (src,dst) pairs: per-block LDS histogram, one global
//     reservation atomic per (block,bucket), LDS cursors for intra-block append.
__global__ __launch_bounds__(256) void pair_place_kernel(const int* __restrict__ ei,
        int* __restrict__ bcursor, int2* __restrict__ pairs) {
    __shared__ int hist[NBKT];
    __shared__ int cur[NBKT];
    int tid = threadIdx.x;
    for (int i = tid; i < NBKT; i += 256) hist[i] = 0;
    __syncthreads();
    int base = blockIdx.x * CHUNK;
    for (int it = 0; it < CHUNK / 256; ++it) {
        int d = ei[N_EDGES + base + it * 256 + tid];
        atomicAdd(&hist[d >> BSH], 1);
    }
    __syncthreads();
    for (int i = tid; i < NBKT; i += 256)
        cur[i] = hist[i] ? atomicAdd(&bcursor[i], hist[i]) : 0;
    __syncthreads();
    for (int it = 0; it < CHUNK / 256; ++it) {
        int e = base + it * 256 + tid;
        int s = ei[e], d = ei[N_EDGES + e];
        int pos = atomicAdd(&cur[d >> BSH], 1);
        pairs[pos] = make_int2(s, d);
    }
}

// k4) per-bucket finish (fused): node degrees (LDS) -> local scan -> offs & inv
//     -> place srcs into the bucket's contiguous region. One block per bucket.
__global__ __launch_bounds__(256) void bucket_finish_kernel(const int2* __restrict__ pairs,
        const int* __restrict__ boffs, int* __restrict__ offs,
        float* __restrict__ inv, int* __restrict__ srcs) {
    __shared__ int deg[NPB];
    __shared__ int cur[NPB];
    __shared__ int wsum2[2];
    int tid = threadIdx.x;
    int b = blockIdx.x;
    int nbase = b << BSH;
    int eb = boffs[b], ee = boffs[b + 1];
    if (tid < NPB) deg[tid] = 0;
    __syncthreads();
    for (int j = eb + tid; j < ee; j += 256)
        atomicAdd(&deg[pairs[j].y & (NPB - 1)], 1);
    __syncthreads();
    if (tid < NPB) {                       // 2 full waves: exclusive scan of deg
        int lane = tid & 63, w = tid >> 6;
        int v = deg[tid];
        int incl = v;
        #pragma unroll
        for (int off = 1; off < 64; off <<= 1) {
            int t = __shfl_up(incl, off);
            if (lane >= off) incl += t;
        }
        if (lane == 63) wsum2[w] = incl;
        __syncthreads();
        int excl = incl - v + ((w == 1) ? wsum2[0] : 0);
        int start = eb + excl;
        cur[tid] = start;
        int n = nbase + tid;
        if (n < N_NODES) {
            offs[n] = start;
            inv[n] = rsqrtf((float)(v + 1));
        }
    } else {
        __syncthreads();                   // match the scan's barrier
    }
    __syncthreads();
    for (int j = eb + tid; j < ee; j += 256) {
        int2 p = pairs[j];
        int pos = atomicAdd(&cur[p.y & (NPB - 1)], 1);
        srcs[pos] = p.x;
    }
}

// ---------------------------------------------------------------------------
// 5) xs[n] = inv[n]*x[n]
__global__ void scale_x_kernel(const float4* __restrict__ x, const float* __restrict__ inv,
                               float4* __restrict__ xs) {
    int n = blockIdx.x * blockDim.x + threadIdx.x;
    if (n < N_NODES) {
        float s = inv[n];
        float4 v = x[n];
        v.x *= s; v.y *= s; v.z *= s; v.w *= s;
        xs[n] = v;
    }
}

// 6) gather-aggregate layer 1: aggX[n] = xs[n] + sum_{src in N(n)} xs[src]
__global__ void agg1_kernel(const float4* __restrict__ xs, const int* __restrict__ offs,
                            const int* __restrict__ srcs, float4* __restrict__ aggX) {
    int n = blockIdx.x * blockDim.x + threadIdx.x;
    if (n >= N_NODES) return;
    float4 acc = xs[n];
    int b = offs[n], e = offs[n + 1];
    for (int j = b; j < e; ++j) acc = f4add(acc, xs[srcs[j]]);
    aggX[n] = acc;
}

// 7) h1[n][c] = relu( (inv[n]*aggX[n]) @ W1[:,c] + b1[c] )
__global__ __launch_bounds__(256) void gemm1_kernel(const float4* __restrict__ aggX,
        const float* __restrict__ inv, const float* __restrict__ W1,
        const float* __restrict__ b1, float4* __restrict__ h1) {
    __shared__ float w[4 * C1];
    __shared__ float bs[C1];
    int tid = threadIdx.x;
    w[tid] = W1[tid]; w[tid + 256] = W1[tid + 256];
    if (tid < C1) bs[tid] = b1[tid];
    __syncthreads();
    int gid = blockIdx.x * 256 + tid;
    int q = gid & 31;
    int n = gid >> 5;
    if (n >= N_NODES) return;
    float s = inv[n];
    float4 t = aggX[n];
    t.x *= s; t.y *= s; t.z *= s; t.w *= s;
    int c = q * 4;
    float4 o;
    o.x = fmaxf(t.x*w[c+0] + t.y*w[C1+c+0] + t.z*w[2*C1+c+0] + t.w*w[3*C1+c+0] + bs[c+0], 0.f);
    o.y = fmaxf(t.x*w[c+1] + t.y*w[C1+c+1] + t.z*w[2*C1+c+1] + t.w*w[3*C1+c+1] + bs[c+1], 0.f);
    o.z = fmaxf(t.x*w[c+2] + t.y*w[C1+c+2] + t.z*w[2*C1+c+2] + t.w*w[3*C1+c+2] + bs[c+2], 0.f);
    o.w = fmaxf(t.x*w[c+3] + t.y*w[C1+c+3] + t.z*w[2*C1+c+3] + t.w*w[3*C1+c+3] + bs[c+3], 0.f);
    h1[(size_t)n * 32 + q] = o;
}

// 8) hs2[n] = inv[n]*(h1[n] @ W2)
__global__ __launch_bounds__(256) void gemm2_kernel(const float* __restrict__ h1,
        const float* __restrict__ W2, const float* __restrict__ inv,
        float4* __restrict__ hs2) {
    __shared__ float w[C1 * C2];     // 32 KB
    __shared__ float rows[64 * C1];  // 32 KB
    int tid = threadIdx.x;
    int base = blockIdx.x * 64;
    for (int i = tid; i < C1 * C2; i += 256) w[i] = W2[i];
    {
        const float4* h4 = (const float4*)(h1 + (size_t)base * C1);
        float4* r4 = (float4*)rows;
        int lim = (N_NODES - base < 64 ? N_NODES - base : 64) * (C1 / 4);
        for (int i = tid; i < 64 * (C1 / 4); i += 256)
            if (i < lim) r4[i] = h4[i];
    }
    __syncthreads();
    int q = tid & 15;
    int ng = tid >> 4;
    float4 acc[4];
    #pragma unroll
    for (int j = 0; j < 4; ++j) acc[j] = make_float4(0.f, 0.f, 0.f, 0.f);
    #pragma unroll 4
    for (int k = 0; k < C1; ++k) {
        float4 wv = *(const float4*)(w + k * C2 + q * 4);
        #pragma unroll
        for (int j = 0; j < 4; ++j) {
            float r = rows[(ng * 4 + j) * C1 + k];
            acc[j].x += r * wv.x; acc[j].y += r * wv.y;
            acc[j].z += r * wv.z; acc[j].w += r * wv.w;
        }
    }
    #pragma unroll
    for (int j = 0; j < 4; ++j) {
        int n = base + ng * 4 + j;
        if (n < N_NODES) {
            float s = inv[n];
            float4 o = acc[j];
            o.x *= s; o.y *= s; o.z *= s; o.w *= s;
            hs2[(size_t)n * (C2 / 4) + q] = o;
        }
    }
}

// 9) gather-aggregate layer 2 + epilogue: z = inv*(hs2[n] + sum hs2[src]) + b2
__global__ void agg2_kernel(const float4* __restrict__ hs2, const int* __restrict__ offs,
                            const int* __restrict__ srcs, const float* __restrict__ inv,
                            const float4* __restrict__ b2, float4* __restrict__ z) {
    int gid = blockIdx.x * blockDim.x + threadIdx.x;
    int n = gid >> 4;
    if (n >= N_NODES) return;
    int q = gid & 15;
    float4 acc = hs2[(size_t)n * 16 + q];
    int b = offs[n], e = offs[n + 1];
    for (int j = b; j < e; ++j) {
        int s = srcs[j];
        acc = f4add(acc, hs2[(size_t)s * 16 + q]);
    }
    float s = inv[n];
    float4 bb = b2[q];
    acc.x = acc.x * s + bb.x; acc.y = acc.y * s + bb.y;
    acc.z = acc.z * s + bb.z; acc.w = acc.w * s + bb.w;
    z[(size_t)n * 16 + q] = acc;
}

// 10) decode: logits[e] = dot(z[a], z[b])   (16 lanes / edge, xor-shuffle reduce)
__global__ void decode_kernel(const int* __restrict__ eli, const float4* __restrict__ z,
                              float* __restrict__ out) {
    int gid = blockIdx.x * blockDim.x + threadIdx.x;
    int e = gid >> 4;
    if (e >= N_LBL) return;
    int q = gid & 15;
    int a = eli[e], b = eli[N_LBL + e];
    float4 va = z[(size_t)a * 16 + q];
    float4 vb = z[(size_t)b * 16 + q];
    float p = va.x * vb.x + va.y * vb.y + va.z * vb.z + va.w * vb.w;
    p += __shfl_xor(p, 8);
    p += __shfl_xor(p, 4);
    p += __shfl_xor(p, 2);
    p += __shfl_xor(p, 1);
    if (q == 0) out[e] = p;
}

extern "C" void kernel_launch(void* const* d_in, const int* in_sizes, int n_in,
                              void* d_out, int out_size, void* d_ws, size_t ws_size,
                              hipStream_t stream) {
    const float* x  = (const float*)d_in[0];
    const int*   ei = (const int*)d_in[1];
    const int*  eli = (const int*)d_in[2];
    const float* W1 = (const float*)d_in[3];
    const float* b1 = (const float*)d_in[4];
    const float* W2 = (const float*)d_in[5];
    const float* b2 = (const float*)d_in[6];
    float* out = (float*)d_out;

    // workspace layout (16B aligned). pairs & z alias h1 (dead ranges).
    char* p = (char*)d_ws;
    int*   bucket_total = (int*)p;  p += 1024 * 4;
    int*   boffs        = (int*)p;  p += 1024 * 4;
    int*   bcursor      = (int*)p;  p += 1024 * 4;
    int*   offs         = (int*)p;  p += (size_t)(N_NODES + 4) * 4;
    float* inv          = (float*)p; p += (size_t)N_NODES * 4;
    int*   srcs         = (int*)p;  p += (size_t)N_EDGES * 4;
    float* xs           = (float*)p; p += (size_t)N_NODES * 16;
    float* aggX         = (float*)p; p += (size_t)N_NODES * 16;
    float* h1           = (float*)p; p += (size_t)N_NODES * C1 * 4;  // 51.2 MB
    float* hs2          = (float*)p; p += (size_t)N_NODES * C2 * 4;  // 25.6 MB
    int2*  pairs        = (int2*)h1;  // 25.6 MB, dead before gemm1 writes h1
    float* z            = h1;         // 25.6 MB, h1 dead after gemm2

    hipMemsetAsync(bucket_total, 0, 1024 * 4, stream);
    count_kernel<<<NCB, 256, 0, stream>>>(ei, bucket_total);
    bscan_kernel<<<1, 1024, 0, stream>>>(bucket_total, boffs, bcursor, offs);
    pair_place_kernel<<<NCB, 256, 0, stream>>>(ei, bcursor, pairs);
    bucket_finish_kernel<<<NBKT, 256, 0, stream>>>(pairs, boffs, offs, inv, srcs);
    scale_x_kernel<<<(N_NODES + 255) / 256, 256, 0, stream>>>((const float4*)x, inv,
                                                              (float4*)xs);
    agg1_kernel<<<(N_NODES + 255) / 256, 256, 0, stream>>>((const float4*)xs, offs, srcs,
                                                           (float4*)aggX);
    gemm1_kernel<<<(N_NODES * 32 + 255) / 256, 256, 0, stream>>>((const float4*)aggX, inv,
                                                                 W1, b1, (float4*)h1);
    gemm2_kernel<<<(N_NODES + 63) / 64, 256, 0, stream>>>(h1, W2, inv, (float4*)hs2);
    agg2_kernel<<<((size_t)N_NODES * 16 + 255) / 256, 256, 0, stream>>>(
        (const float4*)hs2, offs, srcs, inv, (const float4*)b2, (float4*)z);
    decode_kernel<<<((size_t)N_LBL * 16 + 255) / 256, 256, 0, stream>>>(
        eli, (const float4*)z, out);
}

// Round 5
// 345.346 us; speedup vs baseline: 10.4572x; 1.2553x over previous
//
#include <hip/hip_runtime.h>

#define N_NODES 100000
#define N_EDGES 3200000
#define N_LBL   200000
#define C1 128
#define C2 64

// bucketing: nodes grouped by (node >> BSH), 128 nodes per bucket
#define BSH   7
#define NPB   128
#define NBKT  ((N_NODES + NPB - 1) / NPB)   // 782
#define NCB   250                            // counting/placing blocks
#define CHUNK (N_EDGES / NCB)                // 12800 edges per block (exact)

#define RSTRIDE 132                          // LDS h1-row stride (128 + 4 pad)

__device__ __forceinline__ float4 f4add(float4 a, float4 b) {
    return make_float4(a.x + b.x, a.y + b.y, a.z + b.z, a.w + b.w);
}
__device__ __forceinline__ unsigned short f2bf(float f) {
    unsigned int u = __float_as_uint(f);
    u += 0x7fff + ((u >> 16) & 1);           // RNE
    return (unsigned short)(u >> 16);
}
__device__ __forceinline__ float bf2f(unsigned short h) {
    return __uint_as_float(((unsigned int)h) << 16);
}

// ---------------------------------------------------------------------------
// k1) per-block LDS histogram of dst-buckets -> global bucket totals
__global__ __launch_bounds__(256) void count_kernel(const int* __restrict__ ei,
                                                    int* __restrict__ bucket_total) {
    __shared__ int hist[NBKT];
    int tid = threadIdx.x;
    for (int i = tid; i < NBKT; i += 256) hist[i] = 0;
    __syncthreads();
    int base = blockIdx.x * CHUNK;
    for (int it = 0; it < CHUNK / 256; ++it) {
        int d = ei[N_EDGES + base + it * 256 + tid];
        atomicAdd(&hist[d >> BSH], 1);
    }
    __syncthreads();
    for (int i = tid; i < NBKT; i += 256)
        if (hist[i]) atomicAdd(&bucket_total[i], hist[i]);
}

// k2) exclusive scan of 782 bucket totals -> boffs[0..782], init bcursor
__global__ __launch_bounds__(1024) void bscan_kernel(const int* __restrict__ bucket_total,
        int* __restrict__ boffs, int* __restrict__ bcursor, int* __restrict__ offs) {
    __shared__ int wsum[16];
    int tid = threadIdx.x;
    int lane = tid & 63, w = tid >> 6;
    int v = (tid < NBKT) ? bucket_total[tid] : 0;
    int incl = v;
    #pragma unroll
    for (int off = 1; off < 64; off <<= 1) {
        int t = __shfl_up(incl, off);
        if (lane >= off) incl += t;
    }
    if (lane == 63) wsum[w] = incl;
    __syncthreads();
    if (w == 0 && lane < 16) {
        int s = wsum[lane];
        #pragma unroll
        for (int off = 1; off < 16; off <<= 1) {
            int t = __shfl_up(s, off);
            if (lane >= off) s += t;
        }
        wsum[lane] = s;
    }
    __syncthreads();
    int excl = incl - v + ((w == 0) ? 0 : wsum[w - 1]);
    if (tid <= NBKT) boffs[tid] = excl;
    if (tid < NBKT)  bcursor[tid] = excl;
    if (tid == 0) offs[N_NODES] = N_EDGES;
}

// k3) bucketize edges into (src,dst) pairs
__global__ __launch_bounds__(256) void pair_place_kernel(const int* __restrict__ ei,
        int* __restrict__ bcursor, int2* __restrict__ pairs) {
    __shared__ int hist[NBKT];
    __shared__ int cur[NBKT];
    int tid = threadIdx.x;
    for (int i = tid; i < NBKT; i += 256) hist[i] = 0;
    __syncthreads();
    int base = blockIdx.x * CHUNK;
    for (int it = 0; it < CHUNK / 256; ++it) {
        int d = ei[N_EDGES + base + it * 256 + tid];
        atomicAdd(&hist[d >> BSH], 1);
    }
    __syncthreads();
    for (int i = tid; i < NBKT; i += 256)
        cur[i] = hist[i] ? atomicAdd(&bcursor[i], hist[i]) : 0;
    __syncthreads();
    for (int it = 0; it < CHUNK / 256; ++it) {
        int e = base + it * 256 + tid;
        int s = ei[e], d = ei[N_EDGES + e];
        int pos = atomicAdd(&cur[d >> BSH], 1);
        pairs[pos] = make_int2(s, d);
    }
}

// k4) per-bucket finish: degrees -> local scan -> offs & inv -> place srcs
__global__ __launch_bounds__(256) void bucket_finish_kernel(const int2* __restrict__ pairs,
        const int* __restrict__ boffs, int* __restrict__ offs,
        float* __restrict__ inv, int* __restrict__ srcs) {
    __shared__ int deg[NPB];
    __shared__ int cur[NPB];
    __shared__ int wsum2[2];
    int tid = threadIdx.x;
    int b = blockIdx.x;
    int nbase = b << BSH;
    int eb = boffs[b], ee = boffs[b + 1];
    if (tid < NPB) deg[tid] = 0;
    __syncthreads();
    for (int j = eb + tid; j < ee; j += 256)
        atomicAdd(&deg[pairs[j].y & (NPB - 1)], 1);
    __syncthreads();
    if (tid < NPB) {
        int lane = tid & 63, w = tid >> 6;
        int v = deg[tid];
        int incl = v;
        #pragma unroll
        for (int off = 1; off < 64; off <<= 1) {
            int t = __shfl_up(incl, off);
            if (lane >= off) incl += t;
        }
        if (lane == 63) wsum2[w] = incl;
        __syncthreads();
        int excl = incl - v + ((w == 1) ? wsum2[0] : 0);
        int start = eb + excl;
        cur[tid] = start;
        int n = nbase + tid;
        if (n < N_NODES) {
            offs[n] = start;
            inv[n] = rsqrtf((float)(v + 1));
        }
    } else {
        __syncthreads();
    }
    __syncthreads();
    for (int j = eb + tid; j < ee; j += 256) {
        int2 p = pairs[j];
        int pos = atomicAdd(&cur[p.y & (NPB - 1)], 1);
        srcs[pos] = p.x;
    }
}

// ---------------------------------------------------------------------------
// 5) xs[n] = inv[n]*x[n]
__global__ void scale_x_kernel(const float4* __restrict__ x, const float* __restrict__ inv,
                               float4* __restrict__ xs) {
    int n = blockIdx.x * blockDim.x + threadIdx.x;
    if (n < N_NODES) {
        float s = inv[n];
        float4 v = x[n];
        v.x *= s; v.y *= s; v.z *= s; v.w *= s;
        xs[n] = v;
    }
}

// 6) agg1: 4 lanes/node, neighbor j strided by 4 per lane, shuffle-reduce.
__global__ void agg1_kernel(const float4* __restrict__ xs, const int* __restrict__ offs,
                            const int* __restrict__ srcs, float4* __restrict__ aggX) {
    int gid = blockIdx.x * blockDim.x + threadIdx.x;
    int n = gid >> 2;
    if (n >= N_NODES) return;
    int g = gid & 3;
    float4 acc = (g == 0) ? xs[n] : make_float4(0.f, 0.f, 0.f, 0.f);
    int e = offs[n + 1];
    for (int j = offs[n] + g; j < e; j += 4)
        acc = f4add(acc, xs[srcs[j]]);
    acc.x += __shfl_xor(acc.x, 1); acc.y += __shfl_xor(acc.y, 1);
    acc.z += __shfl_xor(acc.z, 1); acc.w += __shfl_xor(acc.w, 1);
    acc.x += __shfl_xor(acc.x, 2); acc.y += __shfl_xor(acc.y, 2);
    acc.z += __shfl_xor(acc.z, 2); acc.w += __shfl_xor(acc.w, 2);
    if (g == 0) aggX[n] = acc;
}

// 7) fused gemm: hs2b[n] = bf16( inv[n] * relu((inv[n']*aggX)@W1 + b1) @ W2 )
//    64 nodes/block; h1 tile lives only in LDS.
__global__ __launch_bounds__(256) void gemm12_kernel(const float4* __restrict__ aggX,
        const float* __restrict__ inv, const float* __restrict__ W1,
        const float* __restrict__ b1, const float* __restrict__ W2,
        unsigned short* __restrict__ hs2b) {
    __shared__ float w1s[4 * C1];
    __shared__ float bs[C1];
    __shared__ float w2s[C1 * C2];           // 32 KB
    __shared__ float rows[64 * RSTRIDE];     // 33.8 KB (padded stride)
    int tid = threadIdx.x;
    int base = blockIdx.x * 64;
    w1s[tid] = W1[tid];                      // W1 is 512 floats, block is 256:
    w1s[tid + 256] = W1[tid + 256];          // each thread loads BOTH halves
    if (tid < C1) bs[tid] = b1[tid];
    {
        const float4* w4 = (const float4*)W2;
        float4* s4 = (float4*)w2s;
        for (int i = tid; i < C1 * C2 / 4; i += 256) s4[i] = w4[i];
    }
    __syncthreads();
    // Phase A: h1 rows -> LDS. thread = (node nd = tid>>2, part p = tid&3),
    // channels c = p + 4*cc (conflict-free).
    {
        int nd = tid >> 2, p = tid & 3;
        int n = base + nd;
        float4 t = make_float4(0.f, 0.f, 0.f, 0.f);
        float s = 0.f;
        if (n < N_NODES) { t = aggX[n]; s = inv[n]; }
        t.x *= s; t.y *= s; t.z *= s; t.w *= s;
        #pragma unroll 8
        for (int cc = 0; cc < 32; ++cc) {
            int c = p + 4 * cc;
            float h = t.x * w1s[c] + t.y * w1s[C1 + c] + t.z * w1s[2 * C1 + c]
                    + t.w * w1s[3 * C1 + c] + bs[c];
            rows[nd * RSTRIDE + c] = fmaxf(h, 0.f);
        }
    }
    __syncthreads();
    // Phase B: 16 col-quads x 16 node-groups (4 nodes each)
    int q = tid & 15;
    int ng = tid >> 4;
    float4 acc[4];
    #pragma unroll
    for (int j = 0; j < 4; ++j) acc[j] = make_float4(0.f, 0.f, 0.f, 0.f);
    #pragma unroll 4
    for (int k = 0; k < C1; ++k) {
        float4 wv = *(const float4*)(w2s + k * C2 + q * 4);
        #pragma unroll
        for (int j = 0; j < 4; ++j) {
            float r = rows[(ng * 4 + j) * RSTRIDE + k];
            acc[j].x += r * wv.x; acc[j].y += r * wv.y;
            acc[j].z += r * wv.z; acc[j].w += r * wv.w;
        }
    }
    #pragma unroll
    for (int j = 0; j < 4; ++j) {
        int n = base + ng * 4 + j;
        if (n < N_NODES) {
            float s = inv[n];
            ushort4 o;
            o.x = f2bf(acc[j].x * s); o.y = f2bf(acc[j].y * s);
            o.z = f2bf(acc[j].z * s); o.w = f2bf(acc[j].w * s);
            *((ushort4*)(hs2b + (size_t)n * C2) + q) = o;
        }
    }
}

// 9) agg2: one 64-lane wave per node; 16 ch-quads x 4 neighbor slots in flight.
//    z = inv*(hs2[n] + sum hs2[src]) + b2
__global__ void agg2_kernel(const unsigned short* __restrict__ hs2b,
                            const int* __restrict__ offs, const int* __restrict__ srcs,
                            const float* __restrict__ inv, const float4* __restrict__ b2,
                            float4* __restrict__ z) {
    int gid = blockIdx.x * blockDim.x + threadIdx.x;
    int n = gid >> 6;
    if (n >= N_NODES) return;
    int lane = gid & 63;
    int q = lane & 15;          // channel quad
    int g = lane >> 4;          // neighbor slot 0..3
    float4 acc = make_float4(0.f, 0.f, 0.f, 0.f);
    if (g == 0) {
        ushort4 v = *((const ushort4*)(hs2b + (size_t)n * C2) + q);
        acc.x = bf2f(v.x); acc.y = bf2f(v.y); acc.z = bf2f(v.z); acc.w = bf2f(v.w);
    }
    int e = offs[n + 1];
    for (int j = offs[n] + g; j < e; j += 4) {
        int s = srcs[j];
        ushort4 v = *((const ushort4*)(hs2b + (size_t)s * C2) + q);
        acc.x += bf2f(v.x); acc.y += bf2f(v.y);
        acc.z += bf2f(v.z); acc.w += bf2f(v.w);
    }
    acc.x += __shfl_xor(acc.x, 16); acc.y += __shfl_xor(acc.y, 16);
    acc.z += __shfl_xor(acc.z, 16); acc.w += __shfl_xor(acc.w, 16);
    acc.x += __shfl_xor(acc.x, 32); acc.y += __shfl_xor(acc.y, 32);
    acc.z += __shfl_xor(acc.z, 32); acc.w += __shfl_xor(acc.w, 32);
    if (g == 0) {
        float s = inv[n];
        float4 bb = b2[q];
        acc.x = acc.x * s + bb.x; acc.y = acc.y * s + bb.y;
        acc.z = acc.z * s + bb.z; acc.w = acc.w * s + bb.w;
        z[(size_t)n * 16 + q] = acc;
    }
}

// 10) decode: logits[e] = dot(z[a], z[b])
__global__ void decode_kernel(const int* __restrict__ eli, const float4* __restrict__ z,
                              float* __restrict__ out) {
    int gid = blockIdx.x * blockDim.x + threadIdx.x;
    int e = gid >> 4;
    if (e >= N_LBL) return;
    int q = gid & 15;
    int a = eli[e], b = eli[N_LBL + e];
    float4 va = z[(size_t)a * 16 + q];
    float4 vb = z[(size_t)b * 16 + q];
    float p = va.x * vb.x + va.y * vb.y + va.z * vb.z + va.w * vb.w;
    p += __shfl_xor(p, 8);
    p += __shfl_xor(p, 4);
    p += __shfl_xor(p, 2);
    p += __shfl_xor(p, 1);
    if (q == 0) out[e] = p;
}

extern "C" void kernel_launch(void* const* d_in, const int* in_sizes, int n_in,
                              void* d_out, int out_size, void* d_ws, size_t ws_size,
                              hipStream_t stream) {
    const float* x  = (const float*)d_in[0];
    const int*   ei = (const int*)d_in[1];
    const int*  eli = (const int*)d_in[2];
    const float* W1 = (const float*)d_in[3];
    const float* b1 = (const float*)d_in[4];
    const float* W2 = (const float*)d_in[5];
    const float* b2 = (const float*)d_in[6];
    float* out = (float*)d_out;

    // workspace layout (16B aligned). z aliases pairs (dead after bucket_finish).
    char* p = (char*)d_ws;
    int*   bucket_total = (int*)p;  p += 1024 * 4;
    int*   boffs        = (int*)p;  p += 1024 * 4;
    int*   bcursor      = (int*)p;  p += 1024 * 4;
    int*   offs         = (int*)p;  p += (size_t)(N_NODES + 4) * 4;
    float* inv          = (float*)p; p += (size_t)N_NODES * 4;
    int*   srcs         = (int*)p;  p += (size_t)N_EDGES * 4;
    float* xs           = (float*)p; p += (size_t)N_NODES * 16;
    float* aggX         = (float*)p; p += (size_t)N_NODES * 16;
    int2*  pairs        = (int2*)p; p += (size_t)N_EDGES * 8;        // 25.6 MB
    unsigned short* hs2b = (unsigned short*)p; p += (size_t)N_NODES * C2 * 2; // 12.8 MB
    float* z            = (float*)pairs;  // 25.6 MB, pairs dead after bucket_finish

    hipMemsetAsync(bucket_total, 0, 1024 * 4, stream);
    count_kernel<<<NCB, 256, 0, stream>>>(ei, bucket_total);
    bscan_kernel<<<1, 1024, 0, stream>>>(bucket_total, boffs, bcursor, offs);
    pair_place_kernel<<<NCB, 256, 0, stream>>>(ei, bcursor, pairs);
    bucket_finish_kernel<<<NBKT, 256, 0, stream>>>(pairs, boffs, offs, inv, srcs);
    scale_x_kernel<<<(N_NODES + 255) / 256, 256, 0, stream>>>((const float4*)x, inv,
                                                              (float4*)xs);
    agg1_kernel<<<(N_NODES * 4 + 255) / 256, 256, 0, stream>>>((const float4*)xs, offs,
                                                               srcs, (float4*)aggX);
    gemm12_kernel<<<(N_NODES + 63) / 64, 256, 0, stream>>>((const float4*)aggX, inv,
                                                           W1, b1, W2, hs2b);
    agg2_kernel<<<((size_t)N_NODES * 64 + 255) / 256, 256, 0, stream>>>(
        hs2b, offs, srcs, inv, (const float4*)b2, (float4*)z);
    decode_kernel<<<((size_t)N_LBL * 16 + 255) / 256, 256, 0, stream>>>(
        eli, (const float4*)z, out);
}

// Round 6
// 288.208 us; speedup vs baseline: 12.5304x; 1.1983x over previous
//
#include <hip/hip_runtime.h>

#define N_NODES 100000
#define N_EDGES 3200000
#define N_LBL   200000
#define C1 128
#define C2 64

// bucketing: nodes grouped by (node >> BSH), 128 nodes per bucket
#define BSH   7
#define NPB   128
#define NBKT  ((N_NODES + NPB - 1) / NPB)   // 782
#define NCB   250                            // placing blocks
#define CHUNK (N_EDGES / NCB)                // 12800 edges per block (exact)
#define CAP   4992                           // slots per bucket (mean 4092, +14 sigma)

#define RSTRIDE 132                          // LDS h1-row stride (128 + 4 pad)

__device__ __forceinline__ float4 f4add(float4 a, float4 b) {
    return make_float4(a.x + b.x, a.y + b.y, a.z + b.z, a.w + b.w);
}
__device__ __forceinline__ unsigned short f2bf(float f) {
    unsigned int u = __float_as_uint(f);
    u += 0x7fff + ((u >> 16) & 1);           // RNE
    return (unsigned short)(u >> 16);
}
__device__ __forceinline__ float bflo(unsigned int u) {
    return __uint_as_float(u << 16);
}
__device__ __forceinline__ float bfhi(unsigned int u) {
    return __uint_as_float(u & 0xffff0000u);
}

// ---------------------------------------------------------------------------
// k0) init per-bucket global cursors to bucket base b*CAP
__global__ void init_kernel(int* __restrict__ gcursor) {
    int b = blockIdx.x * blockDim.x + threadIdx.x;
    if (b < NBKT) gcursor[b] = b * CAP;
}

// k1) bucketize edges into packed u32 (dst_local<<17 | src), fixed-cap buckets.
//     Per-block LDS histogram -> one global reservation atomic per (block,bucket).
__global__ __launch_bounds__(256) void pair_place_kernel(const int* __restrict__ ei,
        int* __restrict__ gcursor, unsigned int* __restrict__ pairs) {
    __shared__ int hist[NBKT];
    __shared__ int cur[NBKT];
    int tid = threadIdx.x;
    for (int i = tid; i < NBKT; i += 256) hist[i] = 0;
    __syncthreads();
    int base = blockIdx.x * CHUNK;
    for (int it = 0; it < CHUNK / 256; ++it) {
        int d = ei[N_EDGES + base + it * 256 + tid];
        atomicAdd(&hist[d >> BSH], 1);
    }
    __syncthreads();
    for (int i = tid; i < NBKT; i += 256)
        cur[i] = hist[i] ? atomicAdd(&gcursor[i], hist[i]) : 0;
    __syncthreads();
    for (int it = 0; it < CHUNK / 256; ++it) {
        int e = base + it * 256 + tid;
        int s = ei[e], d = ei[N_EDGES + e];
        int pos = atomicAdd(&cur[d >> BSH], 1);
        pos = min(pos, NBKT * CAP - 1);      // defensive (never triggers: +14 sigma)
        pairs[pos] = ((unsigned int)(d & (NPB - 1)) << 17) | (unsigned int)s;
    }
}

// k2) per-bucket finish: degrees -> local scan -> offs/ends/inv -> place srcs.
//     Bucket b owns slots [b*CAP, gcursor[b]).
__global__ __launch_bounds__(256) void bucket_finish_kernel(
        const unsigned int* __restrict__ pairs, const int* __restrict__ gcursor,
        int* __restrict__ offs, int* __restrict__ ends,
        float* __restrict__ inv, int* __restrict__ srcs) {
    __shared__ int deg[NPB];
    __shared__ int cur[NPB];
    __shared__ int wsum2[2];
    int tid = threadIdx.x;
    int b = blockIdx.x;
    int nbase = b << BSH;
    int eb = b * CAP, ee = gcursor[b];
    if (tid < NPB) deg[tid] = 0;
    __syncthreads();
    for (int j = eb + tid; j < ee; j += 256)
        atomicAdd(&deg[pairs[j] >> 17], 1);
    __syncthreads();
    if (tid < NPB) {
        int lane = tid & 63, w = tid >> 6;
        int v = deg[tid];
        int incl = v;
        #pragma unroll
        for (int off = 1; off < 64; off <<= 1) {
            int t = __shfl_up(incl, off);
            if (lane >= off) incl += t;
        }
        if (lane == 63) wsum2[w] = incl;
        __syncthreads();
        int excl = incl - v + ((w == 1) ? wsum2[0] : 0);
        int start = eb + excl;
        cur[tid] = start;
        int n = nbase + tid;
        if (n < N_NODES) {
            offs[n] = start;
            ends[n] = start + v;
            inv[n] = rsqrtf((float)(v + 1));
        }
    } else {
        __syncthreads();
    }
    __syncthreads();
    for (int j = eb + tid; j < ee; j += 256) {
        unsigned int p = pairs[j];
        int pos = atomicAdd(&cur[p >> 17], 1);
        srcs[pos] = (int)(p & 0x1FFFFu);
    }
}

// ---------------------------------------------------------------------------
// 3) xs[n] = inv[n]*x[n]
__global__ void scale_x_kernel(const float4* __restrict__ x, const float* __restrict__ inv,
                               float4* __restrict__ xs) {
    int n = blockIdx.x * blockDim.x + threadIdx.x;
    if (n < N_NODES) {
        float s = inv[n];
        float4 v = x[n];
        v.x *= s; v.y *= s; v.z *= s; v.w *= s;
        xs[n] = v;
    }
}

// 4) agg1: 4 lanes/node, neighbor j strided by 4 per lane, shuffle-reduce.
__global__ void agg1_kernel(const float4* __restrict__ xs, const int* __restrict__ offs,
                            const int* __restrict__ ends, const int* __restrict__ srcs,
                            float4* __restrict__ aggX) {
    int gid = blockIdx.x * blockDim.x + threadIdx.x;
    int n = gid >> 2;
    if (n >= N_NODES) return;
    int g = gid & 3;
    float4 acc = (g == 0) ? xs[n] : make_float4(0.f, 0.f, 0.f, 0.f);
    int e = ends[n];
    for (int j = offs[n] + g; j < e; j += 4)
        acc = f4add(acc, xs[srcs[j]]);
    acc.x += __shfl_xor(acc.x, 1); acc.y += __shfl_xor(acc.y, 1);
    acc.z += __shfl_xor(acc.z, 1); acc.w += __shfl_xor(acc.w, 1);
    acc.x += __shfl_xor(acc.x, 2); acc.y += __shfl_xor(acc.y, 2);
    acc.z += __shfl_xor(acc.z, 2); acc.w += __shfl_xor(acc.w, 2);
    if (g == 0) aggX[n] = acc;
}

// 5) fused gemm: hs2b[n] = bf16( inv[n] * relu((inv[n']*aggX)@W1 + b1) @ W2 )
//    64 nodes/block; h1 tile lives only in LDS.
__global__ __launch_bounds__(256) void gemm12_kernel(const float4* __restrict__ aggX,
        const float* __restrict__ inv, const float* __restrict__ W1,
        const float* __restrict__ b1, const float* __restrict__ W2,
        unsigned short* __restrict__ hs2b) {
    __shared__ float w1s[4 * C1];
    __shared__ float bs[C1];
    __shared__ float w2s[C1 * C2];           // 32 KB
    __shared__ float rows[64 * RSTRIDE];     // 33.8 KB (padded stride)
    int tid = threadIdx.x;
    int base = blockIdx.x * 64;
    w1s[tid] = W1[tid];                      // W1 is 512 floats, block is 256:
    w1s[tid + 256] = W1[tid + 256];          // each thread loads BOTH halves
    if (tid < C1) bs[tid] = b1[tid];
    {
        const float4* w4 = (const float4*)W2;
        float4* s4 = (float4*)w2s;
        for (int i = tid; i < C1 * C2 / 4; i += 256) s4[i] = w4[i];
    }
    __syncthreads();
    // Phase A: h1 rows -> LDS. thread = (node nd = tid>>2, part p = tid&3)
    {
        int nd = tid >> 2, p = tid & 3;
        int n = base + nd;
        float4 t = make_float4(0.f, 0.f, 0.f, 0.f);
        float s = 0.f;
        if (n < N_NODES) { t = aggX[n]; s = inv[n]; }
        t.x *= s; t.y *= s; t.z *= s; t.w *= s;
        #pragma unroll 8
        for (int cc = 0; cc < 32; ++cc) {
            int c = p + 4 * cc;
            float h = t.x * w1s[c] + t.y * w1s[C1 + c] + t.z * w1s[2 * C1 + c]
                    + t.w * w1s[3 * C1 + c] + bs[c];
            rows[nd * RSTRIDE + c] = fmaxf(h, 0.f);
        }
    }
    __syncthreads();
    // Phase B: 16 col-quads x 16 node-groups (4 nodes each)
    int q = tid & 15;
    int ng = tid >> 4;
    float4 acc[4];
    #pragma unroll
    for (int j = 0; j < 4; ++j) acc[j] = make_float4(0.f, 0.f, 0.f, 0.f);
    #pragma unroll 4
    for (int k = 0; k < C1; ++k) {
        float4 wv = *(const float4*)(w2s + k * C2 + q * 4);
        #pragma unroll
        for (int j = 0; j < 4; ++j) {
            float r = rows[(ng * 4 + j) * RSTRIDE + k];
            acc[j].x += r * wv.x; acc[j].y += r * wv.y;
            acc[j].z += r * wv.z; acc[j].w += r * wv.w;
        }
    }
    #pragma unroll
    for (int j = 0; j < 4; ++j) {
        int n = base + ng * 4 + j;
        if (n < N_NODES) {
            float s = inv[n];
            ushort4 o;
            o.x = f2bf(acc[j].x * s); o.y = f2bf(acc[j].y * s);
            o.z = f2bf(acc[j].z * s); o.w = f2bf(acc[j].w * s);
            *((ushort4*)(hs2b + (size_t)n * C2) + q) = o;
        }
    }
}

// 6) agg2: one 64-lane wave per node; 8 x 16B-chunk lanes x 8 neighbor slots.
//    z = inv*(hs2[n] + sum hs2[src]) + b2
__global__ void agg2_kernel(const unsigned short* __restrict__ hs2b,
                            const int* __restrict__ offs, const int* __restrict__ ends,
                            const int* __restrict__ srcs, const float* __restrict__ inv,
                            const float4* __restrict__ b2, float4* __restrict__ z) {
    int gid = blockIdx.x * blockDim.x + threadIdx.x;
    int n = gid >> 6;
    if (n >= N_NODES) return;
    int lane = gid & 63;
    int q = lane & 7;           // 16B chunk (8 bf16 channels) within the row
    int g = lane >> 3;          // neighbor slot 0..7
    float acc[8] = {0.f, 0.f, 0.f, 0.f, 0.f, 0.f, 0.f, 0.f};
    if (g == 0) {
        uint4 v = *((const uint4*)(hs2b + (size_t)n * C2) + q);
        acc[0] += bflo(v.x); acc[1] += bfhi(v.x);
        acc[2] += bflo(v.y); acc[3] += bfhi(v.y);
        acc[4] += bflo(v.z); acc[5] += bfhi(v.z);
        acc[6] += bflo(v.w); acc[7] += bfhi(v.w);
    }
    int e = ends[n];
    for (int j = offs[n] + g; j < e; j += 8) {
        int s = srcs[j];
        uint4 v = *((const uint4*)(hs2b + (size_t)s * C2) + q);
        acc[0] += bflo(v.x); acc[1] += bfhi(v.x);
        acc[2] += bflo(v.y); acc[3] += bfhi(v.y);
        acc[4] += bflo(v.z); acc[5] += bfhi(v.z);
        acc[6] += bflo(v.w); acc[7] += bfhi(v.w);
    }
    #pragma unroll
    for (int k = 0; k < 8; ++k) {
        acc[k] += __shfl_xor(acc[k], 8);
        acc[k] += __shfl_xor(acc[k], 16);
        acc[k] += __shfl_xor(acc[k], 32);
    }
    if (g == 0) {
        float s = inv[n];
        float4 b0 = b2[q * 2], b1v = b2[q * 2 + 1];
        float4 o0 = make_float4(acc[0] * s + b0.x, acc[1] * s + b0.y,
                                acc[2] * s + b0.z, acc[3] * s + b0.w);
        float4 o1 = make_float4(acc[4] * s + b1v.x, acc[5] * s + b1v.y,
                                acc[6] * s + b1v.z, acc[7] * s + b1v.w);
        z[(size_t)n * 16 + q * 2]     = o0;
        z[(size_t)n * 16 + q * 2 + 1] = o1;
    }
}

// 7) decode: logits[e] = dot(z[a], z[b])
__global__ void decode_kernel(const int* __restrict__ eli, const float4* __restrict__ z,
                              float* __restrict__ out) {
    int gid = blockIdx.x * blockDim.x + threadIdx.x;
    int e = gid >> 4;
    if (e >= N_LBL) return;
    int q = gid & 15;
    int a = eli[e], b = eli[N_LBL + e];
    float4 va = z[(size_t)a * 16 + q];
    float4 vb = z[(size_t)b * 16 + q];
    float p = va.x * vb.x + va.y * vb.y + va.z * vb.z + va.w * vb.w;
    p += __shfl_xor(p, 8);
    p += __shfl_xor(p, 4);
    p += __shfl_xor(p, 2);
    p += __shfl_xor(p, 1);
    if (q == 0) out[e] = p;
}

extern "C" void kernel_launch(void* const* d_in, const int* in_sizes, int n_in,
                              void* d_out, int out_size, void* d_ws, size_t ws_size,
                              hipStream_t stream) {
    const float* x  = (const float*)d_in[0];
    const int*   ei = (const int*)d_in[1];
    const int*  eli = (const int*)d_in[2];
    const float* W1 = (const float*)d_in[3];
    const float* b1 = (const float*)d_in[4];
    const float* W2 = (const float*)d_in[5];
    const float* b2 = (const float*)d_in[6];
    float* out = (float*)d_out;

    // workspace layout (all 16B aligned). Total ~74 MB.
    char* p = (char*)d_ws;
    int*   gcursor = (int*)p;   p += 1024 * 4;
    int*   offs    = (int*)p;   p += (size_t)N_NODES * 4;
    int*   ends    = (int*)p;   p += (size_t)N_NODES * 4;
    float* inv     = (float*)p; p += (size_t)N_NODES * 4;
    unsigned int* pairs = (unsigned int*)p; p += (size_t)NBKT * CAP * 4;  // 15.6 MB
    int*   srcs    = (int*)p;   p += (size_t)NBKT * CAP * 4;              // 15.6 MB
    float* xs      = (float*)p; p += (size_t)N_NODES * 16;
    float* aggX    = (float*)p; p += (size_t)N_NODES * 16;
    unsigned short* hs2b = (unsigned short*)p; p += (size_t)N_NODES * C2 * 2; // 12.8 MB
    float* z       = (float*)p; p += (size_t)N_NODES * C2 * 4;            // 25.6 MB

    init_kernel<<<(NBKT + 255) / 256, 256, 0, stream>>>(gcursor);
    pair_place_kernel<<<NCB, 256, 0, stream>>>(ei, gcursor, pairs);
    bucket_finish_kernel<<<NBKT, 256, 0, stream>>>(pairs, gcursor, offs, ends, inv, srcs);
    scale_x_kernel<<<(N_NODES + 255) / 256, 256, 0, stream>>>((const float4*)x, inv,
                                                              (float4*)xs);
    agg1_kernel<<<(N_NODES * 4 + 255) / 256, 256, 0, stream>>>((const float4*)xs, offs,
                                                               ends, srcs, (float4*)aggX);
    gemm12_kernel<<<(N_NODES + 63) / 64, 256, 0, stream>>>((const float4*)aggX, inv,
                                                           W1, b1, W2, hs2b);
    agg2_kernel<<<((size_t)N_NODES * 64 + 255) / 256, 256, 0, stream>>>(
        hs2b, offs, ends, srcs, inv, (const float4*)b2, (float4*)z);
    decode_kernel<<<((size_t)N_LBL * 16 + 255) / 256, 256, 0, stream>>>(
        eli, (const float4*)z, out);
}

// Round 7
// 285.407 us; speedup vs baseline: 12.6533x; 1.0098x over previous
//
#include <hip/hip_runtime.h>

#define N_NODES 100000
#define N_EDGES 3200000
#define N_LBL   200000
#define C1 128
#define C2 64

// bucketing: nodes grouped by (node >> BSH), 128 nodes per bucket
#define BSH   7
#define NPB   128
#define NBKT  ((N_NODES + NPB - 1) / NPB)   // 782
#define NCB   250                            // placing blocks
#define CHUNK (N_EDGES / NCB)                // 12800 edges per block (exact)
#define CAP   4992                           // slots per bucket (mean 4092, +14 sigma)

#define RSTRIDE 132                          // LDS h1-row stride (128 + 4 pad)

__device__ __forceinline__ float4 f4add(float4 a, float4 b) {
    return make_float4(a.x + b.x, a.y + b.y, a.z + b.z, a.w + b.w);
}
__device__ __forceinline__ unsigned short f2bf(float f) {
    unsigned int u = __float_as_uint(f);
    u += 0x7fff + ((u >> 16) & 1);           // RNE
    return (unsigned short)(u >> 16);
}
__device__ __forceinline__ float bflo(unsigned int u) {
    return __uint_as_float(u << 16);
}
__device__ __forceinline__ float bfhi(unsigned int u) {
    return __uint_as_float(u & 0xffff0000u);
}

// ---------------------------------------------------------------------------
// k0) init per-bucket global cursors to bucket base b*CAP
__global__ void init_kernel(int* __restrict__ gcursor) {
    int b = blockIdx.x * blockDim.x + threadIdx.x;
    if (b < NBKT) gcursor[b] = b * CAP;
}

// k1) bucketize edges into packed u32 (dst_local<<17 | src), fixed-cap buckets.
//     1024 threads/block: 16 waves/CU to hide the load->LDS-atomic->store chain
//     (256-thr version ran at 9% occupancy, latency-bound).
__global__ __launch_bounds__(1024) void pair_place_kernel(const int* __restrict__ ei,
        int* __restrict__ gcursor, unsigned int* __restrict__ pairs) {
    __shared__ int hist[NBKT];
    __shared__ int cur[NBKT];
    int tid = threadIdx.x;
    for (int i = tid; i < NBKT; i += 1024) hist[i] = 0;
    __syncthreads();
    int base = blockIdx.x * CHUNK;
    for (int e = base + tid; e < base + CHUNK; e += 1024) {
        int d = ei[N_EDGES + e];
        atomicAdd(&hist[d >> BSH], 1);
    }
    __syncthreads();
    for (int i = tid; i < NBKT; i += 1024)
        cur[i] = hist[i] ? atomicAdd(&gcursor[i], hist[i]) : 0;
    __syncthreads();
    for (int e = base + tid; e < base + CHUNK; e += 1024) {
        int s = ei[e], d = ei[N_EDGES + e];
        int pos = atomicAdd(&cur[d >> BSH], 1);
        pos = min(pos, NBKT * CAP - 1);      // defensive (never triggers: +14 sigma)
        pairs[pos] = ((unsigned int)(d & (NPB - 1)) << 17) | (unsigned int)s;
    }
}

// k2) per-bucket finish: degrees -> local scan -> offs/ends/inv/xs -> place srcs.
//     Bucket b owns slots [b*CAP, gcursor[b]). 512 threads for streaming MLP.
__global__ __launch_bounds__(512) void bucket_finish_kernel(
        const unsigned int* __restrict__ pairs, const int* __restrict__ gcursor,
        const float4* __restrict__ x, int* __restrict__ offs, int* __restrict__ ends,
        float* __restrict__ inv, float4* __restrict__ xs, int* __restrict__ srcs) {
    __shared__ int deg[NPB];
    __shared__ int cur[NPB];
    __shared__ int wsum2[2];
    int tid = threadIdx.x;
    int b = blockIdx.x;
    int nbase = b << BSH;
    int eb = b * CAP, ee = gcursor[b];
    if (tid < NPB) deg[tid] = 0;
    __syncthreads();
    for (int j = eb + tid; j < ee; j += 512)
        atomicAdd(&deg[pairs[j] >> 17], 1);
    __syncthreads();
    if (tid < NPB) {
        int lane = tid & 63, w = tid >> 6;
        int v = deg[tid];
        int incl = v;
        #pragma unroll
        for (int off = 1; off < 64; off <<= 1) {
            int t = __shfl_up(incl, off);
            if (lane >= off) incl += t;
        }
        if (lane == 63) wsum2[w] = incl;
        __syncthreads();
        int excl = incl - v + ((w == 1) ? wsum2[0] : 0);
        int start = eb + excl;
        cur[tid] = start;
        int n = nbase + tid;
        if (n < N_NODES) {
            offs[n] = start;
            ends[n] = start + v;
            float iv = rsqrtf((float)(v + 1));
            inv[n] = iv;
            float4 xv = x[n];
            xv.x *= iv; xv.y *= iv; xv.z *= iv; xv.w *= iv;
            xs[n] = xv;
        }
    } else {
        __syncthreads();                     // match the scan's barrier
    }
    __syncthreads();
    for (int j = eb + tid; j < ee; j += 512) {
        unsigned int p = pairs[j];
        int pos = atomicAdd(&cur[p >> 17], 1);
        srcs[pos] = (int)(p & 0x1FFFFu);
    }
}

// ---------------------------------------------------------------------------
// 3) agg1: 4 lanes/node, neighbor j strided by 4 per lane, shuffle-reduce.
__global__ void agg1_kernel(const float4* __restrict__ xs, const int* __restrict__ offs,
                            const int* __restrict__ ends, const int* __restrict__ srcs,
                            float4* __restrict__ aggX) {
    int gid = blockIdx.x * blockDim.x + threadIdx.x;
    int n = gid >> 2;
    if (n >= N_NODES) return;
    int g = gid & 3;
    float4 acc = (g == 0) ? xs[n] : make_float4(0.f, 0.f, 0.f, 0.f);
    int e = ends[n];
    for (int j = offs[n] + g; j < e; j += 4)
        acc = f4add(acc, xs[srcs[j]]);
    acc.x += __shfl_xor(acc.x, 1); acc.y += __shfl_xor(acc.y, 1);
    acc.z += __shfl_xor(acc.z, 1); acc.w += __shfl_xor(acc.w, 1);
    acc.x += __shfl_xor(acc.x, 2); acc.y += __shfl_xor(acc.y, 2);
    acc.z += __shfl_xor(acc.z, 2); acc.w += __shfl_xor(acc.w, 2);
    if (g == 0) aggX[n] = acc;
}

// 4) fused gemm: hs2b[n] = bf16( inv[n] * relu((inv[n']*aggX)@W1 + b1) @ W2 )
//    64 nodes/block; h1 tile lives only in LDS.
__global__ __launch_bounds__(256) void gemm12_kernel(const float4* __restrict__ aggX,
        const float* __restrict__ inv, const float* __restrict__ W1,
        const float* __restrict__ b1, const float* __restrict__ W2,
        unsigned short* __restrict__ hs2b) {
    __shared__ float w1s[4 * C1];
    __shared__ float bs[C1];
    __shared__ float w2s[C1 * C2];           // 32 KB
    __shared__ float rows[64 * RSTRIDE];     // 33.8 KB (padded stride)
    int tid = threadIdx.x;
    int base = blockIdx.x * 64;
    w1s[tid] = W1[tid];                      // W1 is 512 floats, block is 256:
    w1s[tid + 256] = W1[tid + 256];          // each thread loads BOTH halves
    if (tid < C1) bs[tid] = b1[tid];
    {
        const float4* w4 = (const float4*)W2;
        float4* s4 = (float4*)w2s;
        for (int i = tid; i < C1 * C2 / 4; i += 256) s4[i] = w4[i];
    }
    __syncthreads();
    // Phase A: h1 rows -> LDS. thread = (node nd = tid>>2, part p = tid&3)
    {
        int nd = tid >> 2, p = tid & 3;
        int n = base + nd;
        float4 t = make_float4(0.f, 0.f, 0.f, 0.f);
        float s = 0.f;
        if (n < N_NODES) { t = aggX[n]; s = inv[n]; }
        t.x *= s; t.y *= s; t.z *= s; t.w *= s;
        #pragma unroll 8
        for (int cc = 0; cc < 32; ++cc) {
            int c = p + 4 * cc;
            float h = t.x * w1s[c] + t.y * w1s[C1 + c] + t.z * w1s[2 * C1 + c]
                    + t.w * w1s[3 * C1 + c] + bs[c];
            rows[nd * RSTRIDE + c] = fmaxf(h, 0.f);
        }
    }
    __syncthreads();
    // Phase B: 16 col-quads x 16 node-groups (4 nodes each)
    int q = tid & 15;
    int ng = tid >> 4;
    float4 acc[4];
    #pragma unroll
    for (int j = 0; j < 4; ++j) acc[j] = make_float4(0.f, 0.f, 0.f, 0.f);
    #pragma unroll 4
    for (int k = 0; k < C1; ++k) {
        float4 wv = *(const float4*)(w2s + k * C2 + q * 4);
        #pragma unroll
        for (int j = 0; j < 4; ++j) {
            float r = rows[(ng * 4 + j) * RSTRIDE + k];
            acc[j].x += r * wv.x; acc[j].y += r * wv.y;
            acc[j].z += r * wv.z; acc[j].w += r * wv.w;
        }
    }
    #pragma unroll
    for (int j = 0; j < 4; ++j) {
        int n = base + ng * 4 + j;
        if (n < N_NODES) {
            float s = inv[n];
            ushort4 o;
            o.x = f2bf(acc[j].x * s); o.y = f2bf(acc[j].y * s);
            o.z = f2bf(acc[j].z * s); o.w = f2bf(acc[j].w * s);
            *((ushort4*)(hs2b + (size_t)n * C2) + q) = o;
        }
    }
}

// 5) agg2: one 64-lane wave per node; 8 x 16B-chunk lanes x 8 neighbor slots.
//    z = inv*(hs2[n] + sum hs2[src]) + b2
__global__ void agg2_kernel(const unsigned short* __restrict__ hs2b,
                            const int* __restrict__ offs, const int* __restrict__ ends,
                            const int* __restrict__ srcs, const float* __restrict__ inv,
                            const float4* __restrict__ b2, float4* __restrict__ z) {
    int gid = blockIdx.x * blockDim.x + threadIdx.x;
    int n = gid >> 6;
    if (n >= N_NODES) return;
    int lane = gid & 63;
    int q = lane & 7;           // 16B chunk (8 bf16 channels) within the row
    int g = lane >> 3;          // neighbor slot 0..7
    float acc[8] = {0.f, 0.f, 0.f, 0.f, 0.f, 0.f, 0.f, 0.f};
    if (g == 0) {
        uint4 v = *((const uint4*)(hs2b + (size_t)n * C2) + q);
        acc[0] += bflo(v.x); acc[1] += bfhi(v.x);
        acc[2] += bflo(v.y); acc[3] += bfhi(v.y);
        acc[4] += bflo(v.z); acc[5] += bfhi(v.z);
        acc[6] += bflo(v.w); acc[7] += bfhi(v.w);
    }
    int e = ends[n];
    for (int j = offs[n] + g; j < e; j += 8) {
        int s = srcs[j];
        uint4 v = *((const uint4*)(hs2b + (size_t)s * C2) + q);
        acc[0] += bflo(v.x); acc[1] += bfhi(v.x);
        acc[2] += bflo(v.y); acc[3] += bfhi(v.y);
        acc[4] += bflo(v.z); acc[5] += bfhi(v.z);
        acc[6] += bflo(v.w); acc[7] += bfhi(v.w);
    }
    #pragma unroll
    for (int k = 0; k < 8; ++k) {
        acc[k] += __shfl_xor(acc[k], 8);
        acc[k] += __shfl_xor(acc[k], 16);
        acc[k] += __shfl_xor(acc[k], 32);
    }
    if (g == 0) {
        float s = inv[n];
        float4 b0 = b2[q * 2], b1v = b2[q * 2 + 1];
        float4 o0 = make_float4(acc[0] * s + b0.x, acc[1] * s + b0.y,
                                acc[2] * s + b0.z, acc[3] * s + b0.w);
        float4 o1 = make_float4(acc[4] * s + b1v.x, acc[5] * s + b1v.y,
                                acc[6] * s + b1v.z, acc[7] * s + b1v.w);
        z[(size_t)n * 16 + q * 2]     = o0;
        z[(size_t)n * 16 + q * 2 + 1] = o1;
    }
}

// 6) decode: logits[e] = dot(z[a], z[b])
__global__ void decode_kernel(const int* __restrict__ eli, const float4* __restrict__ z,
                              float* __restrict__ out) {
    int gid = blockIdx.x * blockDim.x + threadIdx.x;
    int e = gid >> 4;
    if (e >= N_LBL) return;
    int q = gid & 15;
    int a = eli[e], b = eli[N_LBL + e];
    float4 va = z[(size_t)a * 16 + q];
    float4 vb = z[(size_t)b * 16 + q];
    float p = va.x * vb.x + va.y * vb.y + va.z * vb.z + va.w * vb.w;
    p += __shfl_xor(p, 8);
    p += __shfl_xor(p, 4);
    p += __shfl_xor(p, 2);
    p += __shfl_xor(p, 1);
    if (q == 0) out[e] = p;
}

extern "C" void kernel_launch(void* const* d_in, const int* in_sizes, int n_in,
                              void* d_out, int out_size, void* d_ws, size_t ws_size,
                              hipStream_t stream) {
    const float* x  = (const float*)d_in[0];
    const int*   ei = (const int*)d_in[1];
    const int*  eli = (const int*)d_in[2];
    const float* W1 = (const float*)d_in[3];
    const float* b1 = (const float*)d_in[4];
    const float* W2 = (const float*)d_in[5];
    const float* b2 = (const float*)d_in[6];
    float* out = (float*)d_out;

    // workspace layout (all 16B aligned). Total ~74 MB.
    char* p = (char*)d_ws;
    int*   gcursor = (int*)p;   p += 1024 * 4;
    int*   offs    = (int*)p;   p += (size_t)N_NODES * 4;
    int*   ends    = (int*)p;   p += (size_t)N_NODES * 4;
    float* inv     = (float*)p; p += (size_t)N_NODES * 4;
    unsigned int* pairs = (unsigned int*)p; p += (size_t)NBKT * CAP * 4;  // 15.6 MB
    int*   srcs    = (int*)p;   p += (size_t)NBKT * CAP * 4;              // 15.6 MB
    float* xs      = (float*)p; p += (size_t)N_NODES * 16;
    float* aggX    = (float*)p; p += (size_t)N_NODES * 16;
    unsigned short* hs2b = (unsigned short*)p; p += (size_t)N_NODES * C2 * 2; // 12.8 MB
    float* z       = (float*)p; p += (size_t)N_NODES * C2 * 4;            // 25.6 MB

    init_kernel<<<(NBKT + 255) / 256, 256, 0, stream>>>(gcursor);
    pair_place_kernel<<<NCB, 1024, 0, stream>>>(ei, gcursor, pairs);
    bucket_finish_kernel<<<NBKT, 512, 0, stream>>>(pairs, gcursor, (const float4*)x,
                                                   offs, ends, inv, (float4*)xs, srcs);
    agg1_kernel<<<(N_NODES * 4 + 255) / 256, 256, 0, stream>>>((const float4*)xs, offs,
                                                               ends, srcs, (float4*)aggX);
    gemm12_kernel<<<(N_NODES + 63) / 64, 256, 0, stream>>>((const float4*)aggX, inv,
                                                           W1, b1, W2, hs2b);
    agg2_kernel<<<((size_t)N_NODES * 64 + 255) / 256, 256, 0, stream>>>(
        hs2b, offs, ends, srcs, inv, (const float4*)b2, (float4*)z);
    decode_kernel<<<((size_t)N_LBL * 16 + 255) / 256, 256, 0, stream>>>(
        eli, (const float4*)z, out);
}

// Round 8
// 267.232 us; speedup vs baseline: 13.5139x; 1.0680x over previous
//
#include <hip/hip_runtime.h>

#define N_NODES 100000
#define N_EDGES 3200000
#define N_LBL   200000
#define C1 128
#define C2 64

// bucketing: nodes grouped by (node >> BSH), 128 nodes per bucket
#define BSH   7
#define NPB   128
#define NBKT  ((N_NODES + NPB - 1) / NPB)   // 782
#define NCB   250                            // placing blocks
#define CHUNK (N_EDGES / NCB)                // 12800 edges per block (exact)
#define CAP   4992                           // slots per bucket (mean 4092, +14 sigma)

#define RSTRIDE 132                          // LDS h1-row stride (128 + 4 pad)

__device__ __forceinline__ float4 f4add(float4 a, float4 b) {
    return make_float4(a.x + b.x, a.y + b.y, a.z + b.z, a.w + b.w);
}
__device__ __forceinline__ unsigned short f2bf(float f) {
    unsigned int u = __float_as_uint(f);
    u += 0x7fff + ((u >> 16) & 1);           // RNE
    return (unsigned short)(u >> 16);
}
__device__ __forceinline__ float bflo(unsigned int u) {
    return __uint_as_float(u << 16);
}
__device__ __forceinline__ float bfhi(unsigned int u) {
    return __uint_as_float(u & 0xffff0000u);
}

// ---------------------------------------------------------------------------
// k0) init per-bucket global cursors to bucket base b*CAP
__global__ void init_kernel(int* __restrict__ gcursor) {
    int b = blockIdx.x * blockDim.x + threadIdx.x;
    if (b < NBKT) gcursor[b] = b * CAP;
}

// k1) bucketize edges into packed u32 (dst_local<<17 | src), fixed-cap buckets.
//     Rank-in-register: ONE LDS atomic per edge (hist pass assigns within-block
//     rank, kept in VGPRs); placement is atomic-free. LDS-atomic DS-pipe
//     throughput is the bound (R6: more waves didn't help), so halve the atomics.
__global__ __launch_bounds__(1024) void pair_place_kernel(const int* __restrict__ ei,
        int* __restrict__ gcursor, unsigned int* __restrict__ pairs) {
    __shared__ int hist[NBKT];
    __shared__ int cur[NBKT];
    int tid = threadIdx.x;
    for (int i = tid; i < NBKT; i += 1024) hist[i] = 0;
    __syncthreads();
    int base = blockIdx.x * CHUNK;
    unsigned int pk[13]; int bkt[13]; int rnk[13];
    #pragma unroll
    for (int k = 0; k < 13; ++k) {
        if (k < 12 || tid < CHUNK - 12 * 1024) {     // CHUNK=12800: k=12 covers 512
            int e = base + k * 1024 + tid;
            int s = ei[e], d = ei[N_EDGES + e];
            int b = d >> BSH;
            bkt[k] = b;
            pk[k] = ((unsigned int)(d & (NPB - 1)) << 17) | (unsigned int)s;
            rnk[k] = atomicAdd(&hist[b], 1);
        }
    }
    __syncthreads();
    if (tid < NBKT)
        cur[tid] = hist[tid] ? atomicAdd(&gcursor[tid], hist[tid]) : 0;
    __syncthreads();
    #pragma unroll
    for (int k = 0; k < 13; ++k) {
        if (k < 12 || tid < CHUNK - 12 * 1024) {
            int pos = cur[bkt[k]] + rnk[k];
            pos = min(pos, NBKT * CAP - 1);          // defensive (stat. never)
            pairs[pos] = pk[k];
        }
    }
}

// k2) per-bucket finish: SINGLE pass over pairs (rank-in-register), local scan,
//     offs/ends/inv/xs, then atomic-free placement of srcs.
__global__ __launch_bounds__(512) void bucket_finish_kernel(
        const unsigned int* __restrict__ pairs, const int* __restrict__ gcursor,
        const float4* __restrict__ x, int* __restrict__ offs, int* __restrict__ ends,
        float* __restrict__ inv, float4* __restrict__ xs, int* __restrict__ srcs) {
    __shared__ int deg[NPB];
    __shared__ int nstart[NPB];
    __shared__ int wsum2[2];
    int tid = threadIdx.x;
    int b = blockIdx.x;
    int nbase = b << BSH;
    int eb = b * CAP;
    int ee = min(gcursor[b], eb + CAP);
    if (tid < NPB) deg[tid] = 0;
    __syncthreads();
    unsigned int pk[10]; int rnk[10];                // CAP/512 = 9.75 -> 10 slots
    #pragma unroll
    for (int k = 0; k < 10; ++k) {
        int j = eb + k * 512 + tid;
        if (j < ee) {
            unsigned int p = pairs[j];
            pk[k] = p;
            rnk[k] = atomicAdd(&deg[p >> 17], 1);
        }
    }
    __syncthreads();
    int v = 0, incl = 0;
    if (tid < NPB) {                                 // waves 0-1: scan 128 degrees
        int lane = tid & 63;
        v = deg[tid];
        incl = v;
        #pragma unroll
        for (int off = 1; off < 64; off <<= 1) {
            int t = __shfl_up(incl, off);
            if (lane >= off) incl += t;
        }
        if (lane == 63) wsum2[tid >> 6] = incl;
    }
    __syncthreads();
    if (tid < NPB) {
        int excl = incl - v + ((tid >= 64) ? wsum2[0] : 0);
        int start = eb + excl;
        nstart[tid] = start;
        int n = nbase + tid;
        if (n < N_NODES) {
            offs[n] = start;
            ends[n] = start + v;
            float iv = rsqrtf((float)(v + 1));
            inv[n] = iv;
            float4 xv = x[n];
            xv.x *= iv; xv.y *= iv; xv.z *= iv; xv.w *= iv;
            xs[n] = xv;
        }
    }
    __syncthreads();
    #pragma unroll
    for (int k = 0; k < 10; ++k) {
        int j = eb + k * 512 + tid;
        if (j < ee) {
            unsigned int p = pk[k];
            srcs[nstart[p >> 17] + rnk[k]] = (int)(p & 0x1FFFFu);
        }
    }
}

// ---------------------------------------------------------------------------
// 3) agg1: 4 lanes/node, neighbor j strided by 4 per lane, shuffle-reduce.
__global__ void agg1_kernel(const float4* __restrict__ xs, const int* __restrict__ offs,
                            const int* __restrict__ ends, const int* __restrict__ srcs,
                            float4* __restrict__ aggX) {
    int gid = blockIdx.x * blockDim.x + threadIdx.x;
    int n = gid >> 2;
    if (n >= N_NODES) return;
    int g = gid & 3;
    float4 acc = (g == 0) ? xs[n] : make_float4(0.f, 0.f, 0.f, 0.f);
    int e = ends[n];
    for (int j = offs[n] + g; j < e; j += 4)
        acc = f4add(acc, xs[srcs[j]]);
    acc.x += __shfl_xor(acc.x, 1); acc.y += __shfl_xor(acc.y, 1);
    acc.z += __shfl_xor(acc.z, 1); acc.w += __shfl_xor(acc.w, 1);
    acc.x += __shfl_xor(acc.x, 2); acc.y += __shfl_xor(acc.y, 2);
    acc.z += __shfl_xor(acc.z, 2); acc.w += __shfl_xor(acc.w, 2);
    if (g == 0) aggX[n] = acc;
}

// 4) fused gemm: hs2b[n] = bf16( inv[n] * relu((inv[n']*aggX)@W1 + b1) @ W2 )
//    64 nodes/block; h1 tile lives only in LDS.
__global__ __launch_bounds__(256) void gemm12_kernel(const float4* __restrict__ aggX,
        const float* __restrict__ inv, const float* __restrict__ W1,
        const float* __restrict__ b1, const float* __restrict__ W2,
        unsigned short* __restrict__ hs2b) {
    __shared__ float w1s[4 * C1];
    __shared__ float bs[C1];
    __shared__ float w2s[C1 * C2];           // 32 KB
    __shared__ float rows[64 * RSTRIDE];     // 33.8 KB (padded stride)
    int tid = threadIdx.x;
    int base = blockIdx.x * 64;
    w1s[tid] = W1[tid];                      // W1 is 512 floats, block is 256:
    w1s[tid + 256] = W1[tid + 256];          // each thread loads BOTH halves
    if (tid < C1) bs[tid] = b1[tid];
    {
        const float4* w4 = (const float4*)W2;
        float4* s4 = (float4*)w2s;
        for (int i = tid; i < C1 * C2 / 4; i += 256) s4[i] = w4[i];
    }
    __syncthreads();
    // Phase A: h1 rows -> LDS. thread = (node nd = tid>>2, part p = tid&3)
    {
        int nd = tid >> 2, p = tid & 3;
        int n = base + nd;
        float4 t = make_float4(0.f, 0.f, 0.f, 0.f);
        float s = 0.f;
        if (n < N_NODES) { t = aggX[n]; s = inv[n]; }
        t.x *= s; t.y *= s; t.z *= s; t.w *= s;
        #pragma unroll 8
        for (int cc = 0; cc < 32; ++cc) {
            int c = p + 4 * cc;
            float h = t.x * w1s[c] + t.y * w1s[C1 + c] + t.z * w1s[2 * C1 + c]
                    + t.w * w1s[3 * C1 + c] + bs[c];
            rows[nd * RSTRIDE + c] = fmaxf(h, 0.f);
        }
    }
    __syncthreads();
    // Phase B: 16 col-quads x 16 node-groups (4 nodes each)
    int q = tid & 15;
    int ng = tid >> 4;
    float4 acc[4];
    #pragma unroll
    for (int j = 0; j < 4; ++j) acc[j] = make_float4(0.f, 0.f, 0.f, 0.f);
    #pragma unroll 4
    for (int k = 0; k < C1; ++k) {
        float4 wv = *(const float4*)(w2s + k * C2 + q * 4);
        #pragma unroll
        for (int j = 0; j < 4; ++j) {
            float r = rows[(ng * 4 + j) * RSTRIDE + k];
            acc[j].x += r * wv.x; acc[j].y += r * wv.y;
            acc[j].z += r * wv.z; acc[j].w += r * wv.w;
        }
    }
    #pragma unroll
    for (int j = 0; j < 4; ++j) {
        int n = base + ng * 4 + j;
        if (n < N_NODES) {
            float s = inv[n];
            ushort4 o;
            o.x = f2bf(acc[j].x * s); o.y = f2bf(acc[j].y * s);
            o.z = f2bf(acc[j].z * s); o.w = f2bf(acc[j].w * s);
            *((ushort4*)(hs2b + (size_t)n * C2) + q) = o;
        }
    }
}

// 5) agg2: one 64-lane wave per node; 8 x 16B-chunk lanes x 8 neighbor slots.
//    zb = bf16( inv*(hs2[n] + sum hs2[src]) + b2 )
__global__ void agg2_kernel(const unsigned short* __restrict__ hs2b,
                            const int* __restrict__ offs, const int* __restrict__ ends,
                            const int* __restrict__ srcs, const float* __restrict__ inv,
                            const float4* __restrict__ b2,
                            unsigned short* __restrict__ zb) {
    int gid = blockIdx.x * blockDim.x + threadIdx.x;
    int n = gid >> 6;
    if (n >= N_NODES) return;
    int lane = gid & 63;
    int q = lane & 7;           // 16B chunk (8 bf16 channels) within the row
    int g = lane >> 3;          // neighbor slot 0..7
    float acc[8] = {0.f, 0.f, 0.f, 0.f, 0.f, 0.f, 0.f, 0.f};
    if (g == 0) {
        uint4 v = *((const uint4*)(hs2b + (size_t)n * C2) + q);
        acc[0] += bflo(v.x); acc[1] += bfhi(v.x);
        acc[2] += bflo(v.y); acc[3] += bfhi(v.y);
        acc[4] += bflo(v.z); acc[5] += bfhi(v.z);
        acc[6] += bflo(v.w); acc[7] += bfhi(v.w);
    }
    int e = ends[n];
    for (int j = offs[n] + g; j < e; j += 8) {
        int s = srcs[j];
        uint4 v = *((const uint4*)(hs2b + (size_t)s * C2) + q);
        acc[0] += bflo(v.x); acc[1] += bfhi(v.x);
        acc[2] += bflo(v.y); acc[3] += bfhi(v.y);
        acc[4] += bflo(v.z); acc[5] += bfhi(v.z);
        acc[6] += bflo(v.w); acc[7] += bfhi(v.w);
    }
    #pragma unroll
    for (int k = 0; k < 8; ++k) {
        acc[k] += __shfl_xor(acc[k], 8);
        acc[k] += __shfl_xor(acc[k], 16);
        acc[k] += __shfl_xor(acc[k], 32);
    }
    if (g == 0) {
        float s = inv[n];
        float4 b0 = b2[q * 2], b1v = b2[q * 2 + 1];
        float o0 = acc[0] * s + b0.x,  o1 = acc[1] * s + b0.y;
        float o2 = acc[2] * s + b0.z,  o3 = acc[3] * s + b0.w;
        float o4 = acc[4] * s + b1v.x, o5 = acc[5] * s + b1v.y;
        float o6 = acc[6] * s + b1v.z, o7 = acc[7] * s + b1v.w;
        uint4 w;
        w.x = (unsigned int)f2bf(o0) | ((unsigned int)f2bf(o1) << 16);
        w.y = (unsigned int)f2bf(o2) | ((unsigned int)f2bf(o3) << 16);
        w.z = (unsigned int)f2bf(o4) | ((unsigned int)f2bf(o5) << 16);
        w.w = (unsigned int)f2bf(o6) | ((unsigned int)f2bf(o7) << 16);
        ((uint4*)(zb + (size_t)n * C2))[q] = w;
    }
}

// 6) decode: logits[e] = dot(zb[a], zb[b])   (8 lanes/edge, bf16 rows)
__global__ void decode_kernel(const int* __restrict__ eli,
                              const unsigned short* __restrict__ zb,
                              float* __restrict__ out) {
    int gid = blockIdx.x * blockDim.x + threadIdx.x;
    int e = gid >> 3;
    if (e >= N_LBL) return;
    int q = gid & 7;
    int a = eli[e], b = eli[N_LBL + e];
    uint4 va = ((const uint4*)zb)[(size_t)a * 8 + q];
    uint4 vb = ((const uint4*)zb)[(size_t)b * 8 + q];
    float p = bflo(va.x) * bflo(vb.x) + bfhi(va.x) * bfhi(vb.x)
            + bflo(va.y) * bflo(vb.y) + bfhi(va.y) * bfhi(vb.y)
            + bflo(va.z) * bflo(vb.z) + bfhi(va.z) * bfhi(vb.z)
            + bflo(va.w) * bflo(vb.w) + bfhi(va.w) * bfhi(vb.w);
    p += __shfl_xor(p, 4);
    p += __shfl_xor(p, 2);
    p += __shfl_xor(p, 1);
    if (q == 0) out[e] = p;
}

extern "C" void kernel_launch(void* const* d_in, const int* in_sizes, int n_in,
                              void* d_out, int out_size, void* d_ws, size_t ws_size,
                              hipStream_t stream) {
    const float* x  = (const float*)d_in[0];
    const int*   ei = (const int*)d_in[1];
    const int*  eli = (const int*)d_in[2];
    const float* W1 = (const float*)d_in[3];
    const float* b1 = (const float*)d_in[4];
    const float* W2 = (const float*)d_in[5];
    const float* b2 = (const float*)d_in[6];
    float* out = (float*)d_out;

    // workspace layout (all 16B aligned). Total ~61 MB.
    char* p = (char*)d_ws;
    int*   gcursor = (int*)p;   p += 1024 * 4;
    int*   offs    = (int*)p;   p += (size_t)N_NODES * 4;
    int*   ends    = (int*)p;   p += (size_t)N_NODES * 4;
    float* inv     = (float*)p; p += (size_t)N_NODES * 4;
    unsigned int* pairs = (unsigned int*)p; p += (size_t)NBKT * CAP * 4;  // 15.6 MB
    int*   srcs    = (int*)p;   p += (size_t)NBKT * CAP * 4;              // 15.6 MB
    float* xs      = (float*)p; p += (size_t)N_NODES * 16;
    float* aggX    = (float*)p; p += (size_t)N_NODES * 16;
    unsigned short* hs2b = (unsigned short*)p; p += (size_t)N_NODES * C2 * 2; // 12.8 MB
    unsigned short* zb   = (unsigned short*)p; p += (size_t)N_NODES * C2 * 2; // 12.8 MB

    init_kernel<<<(NBKT + 255) / 256, 256, 0, stream>>>(gcursor);
    pair_place_kernel<<<NCB, 1024, 0, stream>>>(ei, gcursor, pairs);
    bucket_finish_kernel<<<NBKT, 512, 0, stream>>>(pairs, gcursor, (const float4*)x,
                                                   offs, ends, inv, (float4*)xs, srcs);
    agg1_kernel<<<(N_NODES * 4 + 255) / 256, 256, 0, stream>>>((const float4*)xs, offs,
                                                               ends, srcs, (float4*)aggX);
    gemm12_kernel<<<(N_NODES + 63) / 64, 256, 0, stream>>>((const float4*)aggX, inv,
                                                           W1, b1, W2, hs2b);
    agg2_kernel<<<((size_t)N_NODES * 64 + 255) / 256, 256, 0, stream>>>(
        hs2b, offs, ends, srcs, inv, (const float4*)b2, zb);
    decode_kernel<<<((size_t)N_LBL * 8 + 255) / 256, 256, 0, stream>>>(eli, zb, out);
}

// Round 9
// 255.800 us; speedup vs baseline: 14.1179x; 1.0447x over previous
//
#include <hip/hip_runtime.h>

#define N_NODES 100000
#define N_EDGES 3200000
#define N_LBL   200000
#define C1 128
#define C2 64

// bucketing: nodes grouped by (node >> BSH), 128 nodes per bucket
#define BSH   7
#define NPB   128
#define NBKT  ((N_NODES + NPB - 1) / NPB)   // 782
#define NCB   250                            // placing blocks
#define CHUNK (N_EDGES / NCB)                // 12800 edges per block (exact)
#define CAP   4992                           // slots per bucket (mean 4092, +14 sigma)

#define RSTRIDE 132                          // LDS h1-row stride (128 + 4 pad)

__device__ __forceinline__ float4 f4add(float4 a, float4 b) {
    return make_float4(a.x + b.x, a.y + b.y, a.z + b.z, a.w + b.w);
}
__device__ __forceinline__ unsigned short f2bf(float f) {
    unsigned int u = __float_as_uint(f);
    u += 0x7fff + ((u >> 16) & 1);           // RNE
    return (unsigned short)(u >> 16);
}
__device__ __forceinline__ float bflo(unsigned int u) {
    return __uint_as_float(u << 16);
}
__device__ __forceinline__ float bfhi(unsigned int u) {
    return __uint_as_float(u & 0xffff0000u);
}

// ---------------------------------------------------------------------------
// k1) bucketize edges into packed u32 (dst_local<<17 | src), fixed-cap buckets.
//     gcursor is memset to 0; bucket base b*CAP added at reservation time.
//     Rank-in-register: ONE LDS atomic per edge.
__global__ __launch_bounds__(1024) void pair_place_kernel(const int* __restrict__ ei,
        int* __restrict__ gcursor, unsigned int* __restrict__ pairs) {
    __shared__ int hist[NBKT];
    __shared__ int cur[NBKT];
    int tid = threadIdx.x;
    for (int i = tid; i < NBKT; i += 1024) hist[i] = 0;
    __syncthreads();
    int base = blockIdx.x * CHUNK;
    unsigned int pk[13]; int bkt[13]; int rnk[13];
    #pragma unroll
    for (int k = 0; k < 13; ++k) {
        if (k < 12 || tid < CHUNK - 12 * 1024) {     // CHUNK=12800: k=12 covers 512
            int e = base + k * 1024 + tid;
            int s = ei[e], d = ei[N_EDGES + e];
            int b = d >> BSH;
            bkt[k] = b;
            pk[k] = ((unsigned int)(d & (NPB - 1)) << 17) | (unsigned int)s;
            rnk[k] = atomicAdd(&hist[b], 1);
        }
    }
    __syncthreads();
    if (tid < NBKT) {
        int h = hist[tid];
        cur[tid] = h ? (tid * CAP + atomicAdd(&gcursor[tid], h)) : 0;
    }
    __syncthreads();
    #pragma unroll
    for (int k = 0; k < 13; ++k) {
        if (k < 12 || tid < CHUNK - 12 * 1024) {
            int pos = cur[bkt[k]] + rnk[k];
            pos = min(pos, NBKT * CAP - 1);          // defensive (stat. never)
            pairs[pos] = pk[k];
        }
    }
}

// k2) per-bucket finish: SINGLE pass over pairs (rank-in-register), local scan,
//     offs/ends/inv/xs, then atomic-free placement of srcs.
__global__ __launch_bounds__(512) void bucket_finish_kernel(
        const unsigned int* __restrict__ pairs, const int* __restrict__ gcursor,
        const float4* __restrict__ x, int* __restrict__ offs, int* __restrict__ ends,
        float* __restrict__ inv, float4* __restrict__ xs, int* __restrict__ srcs) {
    __shared__ int deg[NPB];
    __shared__ int nstart[NPB];
    __shared__ int wsum2[2];
    int tid = threadIdx.x;
    int b = blockIdx.x;
    int nbase = b << BSH;
    int eb = b * CAP;
    int ee = eb + min(gcursor[b], CAP);              // gcursor now holds the COUNT
    if (tid < NPB) deg[tid] = 0;
    __syncthreads();
    unsigned int pk[10]; int rnk[10];                // CAP/512 = 9.75 -> 10 slots
    #pragma unroll
    for (int k = 0; k < 10; ++k) {
        int j = eb + k * 512 + tid;
        if (j < ee) {
            unsigned int p = pairs[j];
            pk[k] = p;
            rnk[k] = atomicAdd(&deg[p >> 17], 1);
        }
    }
    __syncthreads();
    int v = 0, incl = 0;
    if (tid < NPB) {                                 // waves 0-1: scan 128 degrees
        int lane = tid & 63;
        v = deg[tid];
        incl = v;
        #pragma unroll
        for (int off = 1; off < 64; off <<= 1) {
            int t = __shfl_up(incl, off);
            if (lane >= off) incl += t;
        }
        if (lane == 63) wsum2[tid >> 6] = incl;
    }
    __syncthreads();
    if (tid < NPB) {
        int excl = incl - v + ((tid >= 64) ? wsum2[0] : 0);
        int start = eb + excl;
        nstart[tid] = start;
        int n = nbase + tid;
        if (n < N_NODES) {
            offs[n] = start;
            ends[n] = start + v;
            float iv = rsqrtf((float)(v + 1));
            inv[n] = iv;
            float4 xv = x[n];
            xv.x *= iv; xv.y *= iv; xv.z *= iv; xv.w *= iv;
            xs[n] = xv;
        }
    }
    __syncthreads();
    #pragma unroll
    for (int k = 0; k < 10; ++k) {
        int j = eb + k * 512 + tid;
        if (j < ee) {
            unsigned int p = pk[k];
            srcs[nstart[p >> 17] + rnk[k]] = (int)(p & 0x1FFFFu);
        }
    }
}

// ---------------------------------------------------------------------------
// 3) fused agg1 + gemm1 + gemm2:
//    aggX gathered into LDS (4 lanes/node), then
//    hs2b[n] = bf16( inv[n] * relu((inv[n]*aggX)@W1 + b1) @ W2 ).
//    64 nodes/block; h1 tile lives only in LDS.
__global__ __launch_bounds__(256) void agg1_gemm12_kernel(
        const float4* __restrict__ xs, const int* __restrict__ offs,
        const int* __restrict__ ends, const int* __restrict__ srcs,
        const float* __restrict__ inv, const float* __restrict__ W1,
        const float* __restrict__ b1, const float* __restrict__ W2,
        unsigned short* __restrict__ hs2b) {
    __shared__ float w1s[4 * C1];
    __shared__ float bs[C1];
    __shared__ float w2s[C1 * C2];           // 32 KB
    __shared__ float rows[64 * RSTRIDE];     // 33.8 KB (padded stride)
    __shared__ float4 aggt[64];              // 1 KB
    int tid = threadIdx.x;
    int base = blockIdx.x * 64;
    w1s[tid] = W1[tid];                      // W1 is 512 floats, block is 256:
    w1s[tid + 256] = W1[tid + 256];          // each thread loads BOTH halves
    if (tid < C1) bs[tid] = b1[tid];
    {
        const float4* w4 = (const float4*)W2;
        float4* s4 = (float4*)w2s;
        for (int i = tid; i < C1 * C2 / 4; i += 256) s4[i] = w4[i];
    }
    // Phase 0: gather aggX for the block's 64 nodes (4 lanes/node, xs is
    // L2-resident 1.6 MB). No barrier needed before: touches only aggt.
    int nd = tid >> 2, g = tid & 3;
    int n = base + nd;
    {
        float4 acc = make_float4(0.f, 0.f, 0.f, 0.f);
        if (n < N_NODES) {
            if (g == 0) acc = xs[n];
            int e = ends[n];
            for (int j = offs[n] + g; j < e; j += 4)
                acc = f4add(acc, xs[srcs[j]]);
        }
        acc.x += __shfl_xor(acc.x, 1); acc.y += __shfl_xor(acc.y, 1);
        acc.z += __shfl_xor(acc.z, 1); acc.w += __shfl_xor(acc.w, 1);
        acc.x += __shfl_xor(acc.x, 2); acc.y += __shfl_xor(acc.y, 2);
        acc.z += __shfl_xor(acc.z, 2); acc.w += __shfl_xor(acc.w, 2);
        if (g == 0) aggt[nd] = acc;
    }
    __syncthreads();
    // Phase A: h1 rows -> LDS. thread = (node nd, part p = g)
    {
        float s = (n < N_NODES) ? inv[n] : 0.f;
        float4 t = aggt[nd];
        t.x *= s; t.y *= s; t.z *= s; t.w *= s;
        #pragma unroll 8
        for (int cc = 0; cc < 32; ++cc) {
            int c = g + 4 * cc;
            float h = t.x * w1s[c] + t.y * w1s[C1 + c] + t.z * w1s[2 * C1 + c]
                    + t.w * w1s[3 * C1 + c] + bs[c];
            rows[nd * RSTRIDE + c] = fmaxf(h, 0.f);
        }
    }
    __syncthreads();
    // Phase B: 16 col-quads x 16 node-groups (4 nodes each)
    int q = tid & 15;
    int ng = tid >> 4;
    float4 acc[4];
    #pragma unroll
    for (int j = 0; j < 4; ++j) acc[j] = make_float4(0.f, 0.f, 0.f, 0.f);
    #pragma unroll 4
    for (int k = 0; k < C1; ++k) {
        float4 wv = *(const float4*)(w2s + k * C2 + q * 4);
        #pragma unroll
        for (int j = 0; j < 4; ++j) {
            float r = rows[(ng * 4 + j) * RSTRIDE + k];
            acc[j].x += r * wv.x; acc[j].y += r * wv.y;
            acc[j].z += r * wv.z; acc[j].w += r * wv.w;
        }
    }
    #pragma unroll
    for (int j = 0; j < 4; ++j) {
        int m = base + ng * 4 + j;
        if (m < N_NODES) {
            float s = inv[m];
            ushort4 o;
            o.x = f2bf(acc[j].x * s); o.y = f2bf(acc[j].y * s);
            o.z = f2bf(acc[j].z * s); o.w = f2bf(acc[j].w * s);
            *((ushort4*)(hs2b + (size_t)m * C2) + q) = o;
        }
    }
}

// 4) agg2: one 64-lane wave per node; 8 x 16B-chunk lanes x 8 neighbor slots,
//    2-row unroll per lane (16 rows in flight per wave).
//    zb = bf16( inv*(hs2[n] + sum hs2[src]) + b2 )
__global__ void agg2_kernel(const unsigned short* __restrict__ hs2b,
                            const int* __restrict__ offs, const int* __restrict__ ends,
                            const int* __restrict__ srcs, const float* __restrict__ inv,
                            const float4* __restrict__ b2,
                            unsigned short* __restrict__ zb) {
    int gid = blockIdx.x * blockDim.x + threadIdx.x;
    int n = gid >> 6;
    if (n >= N_NODES) return;
    int lane = gid & 63;
    int q = lane & 7;           // 16B chunk (8 bf16 channels) within the row
    int g = lane >> 3;          // neighbor slot 0..7
    float acc[8] = {0.f, 0.f, 0.f, 0.f, 0.f, 0.f, 0.f, 0.f};
    if (g == 0) {
        uint4 v = *((const uint4*)(hs2b + (size_t)n * C2) + q);
        acc[0] += bflo(v.x); acc[1] += bfhi(v.x);
        acc[2] += bflo(v.y); acc[3] += bfhi(v.y);
        acc[4] += bflo(v.z); acc[5] += bfhi(v.z);
        acc[6] += bflo(v.w); acc[7] += bfhi(v.w);
    }
    int e = ends[n];
    int j = offs[n] + g;
    for (; j + 8 < e; j += 16) {            // both j and j+8 valid
        int s0 = srcs[j];
        int s1 = srcs[j + 8];
        uint4 v0 = *((const uint4*)(hs2b + (size_t)s0 * C2) + q);
        uint4 v1 = *((const uint4*)(hs2b + (size_t)s1 * C2) + q);
        acc[0] += bflo(v0.x); acc[1] += bfhi(v0.x);
        acc[2] += bflo(v0.y); acc[3] += bfhi(v0.y);
        acc[4] += bflo(v0.z); acc[5] += bfhi(v0.z);
        acc[6] += bflo(v0.w); acc[7] += bfhi(v0.w);
        acc[0] += bflo(v1.x); acc[1] += bfhi(v1.x);
        acc[2] += bflo(v1.y); acc[3] += bfhi(v1.y);
        acc[4] += bflo(v1.z); acc[5] += bfhi(v1.z);
        acc[6] += bflo(v1.w); acc[7] += bfhi(v1.w);
    }
    if (j < e) {
        int s0 = srcs[j];
        uint4 v0 = *((const uint4*)(hs2b + (size_t)s0 * C2) + q);
        acc[0] += bflo(v0.x); acc[1] += bfhi(v0.x);
        acc[2] += bflo(v0.y); acc[3] += bfhi(v0.y);
        acc[4] += bflo(v0.z); acc[5] += bfhi(v0.z);
        acc[6] += bflo(v0.w); acc[7] += bfhi(v0.w);
    }
    #pragma unroll
    for (int k = 0; k < 8; ++k) {
        acc[k] += __shfl_xor(acc[k], 8);
        acc[k] += __shfl_xor(acc[k], 16);
        acc[k] += __shfl_xor(acc[k], 32);
    }
    if (g == 0) {
        float s = inv[n];
        float4 b0 = b2[q * 2], b1v = b2[q * 2 + 1];
        float o0 = acc[0] * s + b0.x,  o1 = acc[1] * s + b0.y;
        float o2 = acc[2] * s + b0.z,  o3 = acc[3] * s + b0.w;
        float o4 = acc[4] * s + b1v.x, o5 = acc[5] * s + b1v.y;
        float o6 = acc[6] * s + b1v.z, o7 = acc[7] * s + b1v.w;
        uint4 w;
        w.x = (unsigned int)f2bf(o0) | ((unsigned int)f2bf(o1) << 16);
        w.y = (unsigned int)f2bf(o2) | ((unsigned int)f2bf(o3) << 16);
        w.z = (unsigned int)f2bf(o4) | ((unsigned int)f2bf(o5) << 16);
        w.w = (unsigned int)f2bf(o6) | ((unsigned int)f2bf(o7) << 16);
        ((uint4*)(zb + (size_t)n * C2))[q] = w;
    }
}

// 5) decode: logits[e] = dot(zb[a], zb[b])   (8 lanes/edge, bf16 rows)
__global__ void decode_kernel(const int* __restrict__ eli,
                              const unsigned short* __restrict__ zb,
                              float* __restrict__ out) {
    int gid = blockIdx.x * blockDim.x + threadIdx.x;
    int e = gid >> 3;
    if (e >= N_LBL) return;
    int q = gid & 7;
    int a = eli[e], b = eli[N_LBL + e];
    uint4 va = ((const uint4*)zb)[(size_t)a * 8 + q];
    uint4 vb = ((const uint4*)zb)[(size_t)b * 8 + q];
    float p = bflo(va.x) * bflo(vb.x) + bfhi(va.x) * bfhi(vb.x)
            + bflo(va.y) * bflo(vb.y) + bfhi(va.y) * bfhi(vb.y)
            + bflo(va.z) * bflo(vb.z) + bfhi(va.z) * bfhi(vb.z)
            + bflo(va.w) * bflo(vb.w) + bfhi(va.w) * bfhi(vb.w);
    p += __shfl_xor(p, 4);
    p += __shfl_xor(p, 2);
    p += __shfl_xor(p, 1);
    if (q == 0) out[e] = p;
}

extern "C" void kernel_launch(void* const* d_in, const int* in_sizes, int n_in,
                              void* d_out, int out_size, void* d_ws, size_t ws_size,
                              hipStream_t stream) {
    const float* x  = (const float*)d_in[0];
    const int*   ei = (const int*)d_in[1];
    const int*  eli = (const int*)d_in[2];
    const float* W1 = (const float*)d_in[3];
    const float* b1 = (const float*)d_in[4];
    const float* W2 = (const float*)d_in[5];
    const float* b2 = (const float*)d_in[6];
    float* out = (float*)d_out;

    // workspace layout (all 16B aligned). Total ~59 MB.
    char* p = (char*)d_ws;
    int*   gcursor = (int*)p;   p += 1024 * 4;
    int*   offs    = (int*)p;   p += (size_t)N_NODES * 4;
    int*   ends    = (int*)p;   p += (size_t)N_NODES * 4;
    float* inv     = (float*)p; p += (size_t)N_NODES * 4;
    unsigned int* pairs = (unsigned int*)p; p += (size_t)NBKT * CAP * 4;  // 15.6 MB
    int*   srcs    = (int*)p;   p += (size_t)NBKT * CAP * 4;              // 15.6 MB
    float* xs      = (float*)p; p += (size_t)N_NODES * 16;
    unsigned short* hs2b = (unsigned short*)p; p += (size_t)N_NODES * C2 * 2; // 12.8 MB
    unsigned short* zb   = (unsigned short*)p; p += (size_t)N_NODES * C2 * 2; // 12.8 MB

    hipMemsetAsync(gcursor, 0, NBKT * 4, stream);
    pair_place_kernel<<<NCB, 1024, 0, stream>>>(ei, gcursor, pairs);
    bucket_finish_kernel<<<NBKT, 512, 0, stream>>>(pairs, gcursor, (const float4*)x,
                                                   offs, ends, inv, (float4*)xs, srcs);
    agg1_gemm12_kernel<<<(N_NODES + 63) / 64, 256, 0, stream>>>(
        (const float4*)xs, offs, ends, srcs, inv, W1, b1, W2, hs2b);
    agg2_kernel<<<((size_t)N_NODES * 64 + 255) / 256, 256, 0, stream>>>(
        hs2b, offs, ends, srcs, inv, (const float4*)b2, zb);
    decode_kernel<<<((size_t)N_LBL * 8 + 255) / 256, 256, 0, stream>>>(eli, zb, out);
}